// Round 3
// baseline (819.267 us; speedup 1.0000x reference)
//
#include <hip/hip_runtime.h>
#include <hip/hip_bf16.h>
#include <stdint.h>

// Problem constants
#define N_ROWS 8192
#define M0C 2672    // C0 + P0 + P1 = 64 + 2080 + 528
#define M1C 2080    // C1 + C0*C1
#define A1C 496
#define P1C 528
#define KP  2688    // M0 padded to multiple of 128 (and 32 for BK)
#define NP2 5888    // NUM_IRREPS (5776) padded to multiple of 256
#define NIR 5776
#define M1P 2112    // M1C padded to multiple of 64
#define NPAD1 2816  // GEMM1 N (=M0) padded to multiple of 256 (11*256)

typedef __attribute__((ext_vector_type(8))) _Float16 half8;
typedef __attribute__((ext_vector_type(4))) float floatx4;

__device__ __forceinline__ void async_copy16(const _Float16* g, _Float16* l) {
  __builtin_amdgcn_global_load_lds(
      (__attribute__((address_space(1))) void*)(g),
      (__attribute__((address_space(3))) void*)(l), 16, 0, 0);
}

// ---------------------------------------------------------------------------
// Transpose + fp32->fp16 convert with zero padding.
// ---------------------------------------------------------------------------
__global__ __launch_bounds__(256) void transpose_cvt_kernel(
    const float* __restrict__ src, _Float16* __restrict__ dst,
    int srcR, int srcC, int dstC) {
  __shared__ float tile[32][33];
  const int t = threadIdx.x, tx = t & 31, ty = t >> 5;
  const int bx = blockIdx.x, by = blockIdx.y;
#pragma unroll
  for (int i = 0; i < 4; ++i) {
    int sr = bx * 32 + ty + i * 8;   // src row (k dim)
    int sc = by * 32 + tx;           // src col
    tile[ty + i * 8][tx] = (sr < srcR && sc < srcC) ? src[(size_t)sr * srcC + sc] : 0.f;
  }
  __syncthreads();
#pragma unroll
  for (int i = 0; i < 4; ++i) {
    int dr = by * 32 + ty + i * 8;
    int dc = bx * 32 + tx;
    dst[(size_t)dr * dstC + dc] = (_Float16)tile[tx][ty + i * 8];
  }
}

// ---------------------------------------------------------------------------
// triu_indices(C) pair decode: p -> (a, b), b >= a.
// ---------------------------------------------------------------------------
__device__ __forceinline__ void triu_ab(int p, int C, int& a, int& b) {
  float fC = (float)C + 0.5f;
  int ai = (int)(fC - sqrtf(fC * fC - 2.0f * (float)p));
  if (ai < 0) ai = 0;
  while (ai > 0 && ai * C - ai * (ai - 1) / 2 > p) --ai;
  while ((ai + 1) * C - (ai + 1) * ai / 2 <= p) ++ai;
  a = ai;
  b = p - (ai * C - ai * (ai - 1) / 2) + ai;
}

// ---------------------------------------------------------------------------
// f0 = [x_s (64) | ss (2080) | vv0 (528) | zero pad (16)]  as fp16 [N][KP]
// ---------------------------------------------------------------------------
__global__ __launch_bounds__(256) void build_f0_kernel(
    const float* __restrict__ xs_g, const float* __restrict__ xv_g,
    _Float16* __restrict__ f0p) {
  __shared__ float xs[64];
  __shared__ float xv[96];
  const int t = threadIdx.x;
  const size_t n = blockIdx.x;
  if (t < 64) xs[t] = xs_g[n * 64 + t];
  else if (t < 160) xv[t - 64] = xv_g[n * 96 + (t - 64)];
  __syncthreads();
  for (int c = t; c < KP; c += 256) {
    float v;
    if (c < 64) {
      v = xs[c];
    } else if (c < 2144) {                       // ss: pair products of x_s
      int a, b;
      triu_ab(c - 64, 64, a, b);
      v = xs[a] * xs[b] * ((a == b) ? 0.70710678118654752f : 1.f);
    } else if (c < M0C) {                        // vv0: pair dots of x_v
      int a, b;
      triu_ab(c - 2144, 32, a, b);
      float d = xv[a * 3] * xv[b * 3] + xv[a * 3 + 1] * xv[b * 3 + 1] +
                xv[a * 3 + 2] * xv[b * 3 + 2];
      v = d * ((a == b) ? 0.70710678118654752f : 1.f) * 0.57735026918962576f;
    } else {
      v = 0.f;                                   // pad
    }
    f0p[n * KP + c] = (_Float16)v;
  }
}

// ---------------------------------------------------------------------------
// fp16 MFMA GEMM, 256x256 tile, BK=32, 8 waves (wave tile 128x64).
// Round-2 change: B is loaded DIRECTLY global->register (double-buffered,
// one K-step ahead) instead of via LDS. The B fragment is a 16-cacheline
// gather L2 serves natively; removing it cuts LDS-pipe demand per K-step
// from ~128 KB (reads+writes) to ~80 KB, below the MFMA pipe's 1242 cyc.
// A keeps a 4-slot LDS ring (64 KiB), staged t+2 ahead (2-barrier-separated
// from last read of the overwritten slot -> provably race-free), counted
// vmcnt(6) steady-state, ONE barrier per K-step, reg-double-buffered A-low
// fragments. B stored transposed [N][K]. Requires K % 128 == 0.
// ---------------------------------------------------------------------------
template <bool SILU>
__global__ __launch_bounds__(512, 2) void gemm256_kernel(
    const _Float16* __restrict__ A, const _Float16* __restrict__ B,
    _Float16* __restrict__ C, int K, int lda, int ldb, int ldc) {
  __shared__ alignas(16) _Float16 As[4 * 8192];   // 4 slots x 256 rows x 32 k
  const int tid = threadIdx.x;

  // XCD-aware bijective remap. 32 row-tiles / 8 XCDs = 4 row-tiles per XCD;
  // sweep cols with 2-row-tile sub-bands so the A sub-band stays L2-resident
  // and B col-tiles are shared by 2 concurrent row-blocks.
  const int ncol = gridDim.x;
  const int id = blockIdx.y * ncol + blockIdx.x;
  const int xcd = id & 7;
  const int j = id >> 3;              // [0, 4*ncol)
  const int hb = j / (2 * ncol);      // 0..1
  const int w = j - hb * 2 * ncol;    // [0, 2*ncol)
  const int by = xcd * 4 + hb * 2 + (w & 1);
  const int bx = w >> 1;
  const size_t row0 = (size_t)by * 256;
  const size_t col0 = (size_t)bx * 256;

  // A staging: 2 chunks per thread per K-tile (16 B each). LDS dest stays
  // lane-contiguous; the XOR swizzle is applied to the global SOURCE chunk.
  const _Float16 *pA0, *pA1;
  _Float16 *lA0, *lA1;
  {
    int c0 = tid, c1 = tid + 512;
    int r0 = c0 >> 2, ch0 = c0 & 3;
    int r1 = c1 >> 2, ch1 = c1 & 3;
    int s0 = ch0 ^ ((r0 >> 1) & 3);
    int s1 = ch1 ^ ((r1 >> 1) & 3);
    pA0 = A + (row0 + r0) * lda + s0 * 8;
    pA1 = A + (row0 + r1) * lda + s1 * 8;
    lA0 = &As[c0 * 8]; lA1 = &As[c1 * 8];
  }

  const int lane = tid & 63;
  const int wv = tid >> 6;       // 0..7
  const int wm = wv & 1;         // M half (128 rows)
  const int wn = wv >> 1;        // N quarter (64 cols)
  const int m16 = lane & 15;
  const int quad = lane >> 4;
  const int sw8 = (quad ^ ((m16 >> 1) & 3)) * 8;   // swizzled read chunk
  const int aoff = (wm * 128 + m16) * 32 + sw8;    // + ii*512

  // B direct-load pointers: lane (m16, quad) reads 16 B of row
  // col0 + wn*64 + jj*16 + m16 at k-offset quad*8 (matches MFMA B layout).
  const _Float16* pB[4];
#pragma unroll
  for (int jj = 0; jj < 4; ++jj)
    pB[jj] = B + (col0 + wn * 64 + jj * 16 + m16) * (size_t)ldb + quad * 8;

  floatx4 acc[8][4] = {};
  half8 aLo0[4], aLo1[4], aHi[4], bRa[4], bRb[4];

#define STAGE(SLOT)                                   \
  {                                                   \
    async_copy16(pA0, lA0 + (SLOT) * 8192);           \
    async_copy16(pA1, lA1 + (SLOT) * 8192);           \
    pA0 += 32; pA1 += 32;                             \
  }

#define BLOAD(BRN)                                    \
  {                                                   \
    _Pragma("unroll")                                 \
    for (int jj = 0; jj < 4; ++jj) {                  \
      BRN[jj] = *(const half8*)pB[jj];                \
      pB[jj] += 32;                                   \
    }                                                 \
  }

  // Per-iter t: stage A(t+2), load B(t+1); vmcnt(6) retires B(t)+A(t+1)
  // (leaves A(t+2)[2] + B(t+1)[4] in flight); barrier; read aHi(t) then
  // aLo(t+1); MFMA-A on {aLo(t), bR(t)} (no lgkm wait), MFMA-B on
  // {aHi(t), bR(t)} (auto lgkmcnt(4)); drain.
#define KITER(BB, ALOC, ALON, BRC, BRN, VMLIT, DO_STAGE, DO_NEXT)             \
  {                                                                           \
    if (DO_STAGE) STAGE(((BB) + 2) & 3);                                      \
    if (DO_NEXT) BLOAD(BRN);                                                  \
    asm volatile("s_waitcnt vmcnt(" VMLIT ")" ::: "memory");                  \
    __builtin_amdgcn_s_barrier();                                             \
    __builtin_amdgcn_sched_barrier(0);                                        \
    _Pragma("unroll")                                                         \
    for (int ii = 0; ii < 4; ++ii)                                            \
      aHi[ii] = *(const half8*)&As[(BB) * 8192 + aoff + (ii + 4) * 512];      \
    if (DO_NEXT) {                                                            \
      _Pragma("unroll")                                                       \
      for (int ii = 0; ii < 4; ++ii)                                          \
        ALON[ii] = *(const half8*)&As[(((BB) + 1) & 3) * 8192 + aoff + ii * 512]; \
    }                                                                         \
    __builtin_amdgcn_sched_barrier(0);                                        \
    __builtin_amdgcn_s_setprio(1);                                            \
    _Pragma("unroll")                                                         \
    for (int ii = 0; ii < 4; ++ii)                                            \
      _Pragma("unroll")                                                       \
      for (int jj = 0; jj < 4; ++jj)                                          \
        acc[ii][jj] = __builtin_amdgcn_mfma_f32_16x16x32_f16(                 \
            ALOC[ii], BRC[jj], acc[ii][jj], 0, 0, 0);                         \
    __builtin_amdgcn_s_setprio(0);                                            \
    __builtin_amdgcn_sched_barrier(0);                                        \
    __builtin_amdgcn_s_setprio(1);                                            \
    _Pragma("unroll")                                                         \
    for (int ii = 0; ii < 4; ++ii)                                            \
      _Pragma("unroll")                                                       \
      for (int jj = 0; jj < 4; ++jj)                                          \
        acc[ii + 4][jj] = __builtin_amdgcn_mfma_f32_16x16x32_f16(             \
            aHi[ii], BRC[jj], acc[ii + 4][jj], 0, 0, 0);                      \
    __builtin_amdgcn_s_setprio(0);                                            \
    asm volatile("s_waitcnt lgkmcnt(0)" ::: "memory");                        \
  }

  // Prologue: stage A(0),A(1); load B(0); confirm A(0); prime aLo0.
  STAGE(0);
  STAGE(1);
  BLOAD(bRa);
  asm volatile("s_waitcnt vmcnt(6)" ::: "memory");   // A(0) landed
  __builtin_amdgcn_s_barrier();
  __builtin_amdgcn_sched_barrier(0);
#pragma unroll
  for (int ii = 0; ii < 4; ++ii) aLo0[ii] = *(const half8*)&As[aoff + ii * 512];

  const int T = K >> 5;               // 84 for K=2688 (divisible by 4)
  for (int t4 = 0; t4 < T - 4; t4 += 4) {
    KITER(0, aLo0, aLo1, bRa, bRb, "6", 1, 1);
    KITER(1, aLo1, aLo0, bRb, bRa, "6", 1, 1);
    KITER(2, aLo0, aLo1, bRa, bRb, "6", 1, 1);
    KITER(3, aLo1, aLo0, bRb, bRa, "6", 1, 1);
  }
  KITER(0, aLo0, aLo1, bRa, bRb, "6", 1, 1);   // t = T-4
  KITER(1, aLo1, aLo0, bRb, bRa, "6", 1, 1);   // t = T-3 (stages A(T-1))
  KITER(2, aLo0, aLo1, bRa, bRb, "4", 0, 1);   // t = T-2 (loads B(T-1))
  KITER(3, aLo1, aLo0, bRb, bRa, "0", 0, 0);   // t = T-1
#undef KITER
#undef BLOAD
#undef STAGE

  // C/D layout: col = lane&15, row = quad*4 + reg
#pragma unroll
  for (int ii = 0; ii < 8; ++ii) {
    size_t r = row0 + wm * 128 + ii * 16 + quad * 4;
#pragma unroll
    for (int jj = 0; jj < 4; ++jj) {
      size_t cc = col0 + wn * 64 + jj * 16 + m16;
#pragma unroll
      for (int rr = 0; rr < 4; ++rr) {
        float v = acc[ii][jj][rr];
        if (SILU) v = v / (1.f + __expf(-v));
        C[(r + rr) * ldc + cc] = (_Float16)v;
      }
    }
  }
}

// ---------------------------------------------------------------------------
// epi0: o0 = (f0 .* g0) @ w0.  32 rows/block, BK=64, K=2688, N=64. grid 256.
// ---------------------------------------------------------------------------
__global__ __launch_bounds__(256) void epi0_kernel(
    const _Float16* __restrict__ f0p, const _Float16* __restrict__ G,
    const _Float16* __restrict__ w0T, float* __restrict__ out) {
  __shared__ alignas(16) _Float16 As[32 * 64];
  const int t = threadIdx.x;
  const size_t n0 = (size_t)blockIdx.x * 32;
  const int lane = t & 63, wave = t >> 6;
  const int m16 = lane & 15, quad = lane >> 4;
  const int rt = (wave & 1) * 16;        // row tile base
  const int ctb = (wave >> 1) * 32;      // col pair base
  const int br = t >> 3, p = t & 7;      // build: row, physical chunk
  const int l8 = (p ^ (br & 7)) * 8;     // logical k offset

  floatx4 acc[2] = {};
  for (int k0 = 0; k0 < KP; k0 += 64) {
    if (k0) __syncthreads();
    {
      half8 f = *(const half8*)&f0p[(n0 + br) * KP + k0 + l8];
      half8 g = *(const half8*)&G[(n0 + br) * NP2 + k0 + l8];
      half8 a;
#pragma unroll
      for (int j = 0; j < 8; ++j) a[j] = (_Float16)((float)f[j] * (float)g[j]);
      *(half8*)&As[br * 64 + p * 8] = a;
    }
    __syncthreads();
#pragma unroll
    for (int kk = 0; kk < 2; ++kk) {
      int q = kk * 4 + quad;
      half8 af = *(const half8*)&As[(rt + m16) * 64 + (q ^ (m16 & 7)) * 8];
#pragma unroll
      for (int c = 0; c < 2; ++c) {
        half8 bf = *(const half8*)&w0T[(size_t)(ctb + c * 16 + m16) * KP + k0 + kk * 32 + quad * 8];
        acc[c] = __builtin_amdgcn_mfma_f32_16x16x32_f16(af, bf, acc[c], 0, 0, 0);
      }
    }
  }
#pragma unroll
  for (int c = 0; c < 2; ++c)
#pragma unroll
    for (int rr = 0; rr < 4; ++rr)
      out[(n0 + rt + quad * 4 + rr) * 288 + ctb + c * 16 + m16] = acc[c][rr];
}

// ---------------------------------------------------------------------------
// epi1: o1[n][o][i] = sum_c f1[n][c][i]*g1[n][c]*w1o[c][o].
// ---------------------------------------------------------------------------
__global__ __launch_bounds__(256) void epi1_kernel(
    const float* __restrict__ xs_g, const float* __restrict__ xv_g,
    const _Float16* __restrict__ G, const _Float16* __restrict__ w1oT,
    float* __restrict__ out) {
  __shared__ float xs[32][64];
  __shared__ float xv[32][96];
  __shared__ alignas(16) _Float16 As[3][32 * 64];
  const int t = threadIdx.x;
  const size_t n0 = (size_t)blockIdx.x * 32;
  for (int idx = t; idx < 32 * 64; idx += 256)
    xs[idx >> 6][idx & 63] = xs_g[(n0 + (idx >> 6)) * 64 + (idx & 63)];
  for (int idx = t; idx < 32 * 96; idx += 256)
    xv[idx / 96][idx % 96] = xv_g[(n0 + idx / 96) * 96 + idx % 96];
  const int lane = t & 63, wave = t >> 6;
  const int m16 = lane & 15, quad = lane >> 4;
  const int rt = (wave & 1) * 16;   // row tile
  const int ct = (wave >> 1) * 16;  // col tile
  const int br = t >> 3, p = t & 7;
  const int l8 = (p ^ (br & 7)) * 8;

  floatx4 acc[3] = {};
  __syncthreads();
  for (int k0 = 0; k0 < M1P; k0 += 64) {
    if (k0) __syncthreads();
    {
      half8 g8 = *(const half8*)&G[(n0 + br) * NP2 + M0C + k0 + l8];
      int kbase = k0 + l8;
      half8 a0, a1, a2;
      if (kbase < 32) {
#pragma unroll
        for (int j = 0; j < 8; ++j) {
          float g = (float)g8[j];
          int v = kbase + j;
          a0[j] = (_Float16)(xv[br][v * 3 + 0] * g);
          a1[j] = (_Float16)(xv[br][v * 3 + 1] * g);
          a2[j] = (_Float16)(xv[br][v * 3 + 2] * g);
        }
      } else {
        int s = (kbase - 32) >> 5;
        if (s > 63) s = 63;                  // pad region: B is zero anyway
        int v0 = (kbase - 32) & 31;
        float xsr = xs[br][s];
#pragma unroll
        for (int j = 0; j < 8; ++j) {
          float g = (float)g8[j] * xsr;
          int v = v0 + j;
          a0[j] = (_Float16)(xv[br][v * 3 + 0] * g);
          a1[j] = (_Float16)(xv[br][v * 3 + 1] * g);
          a2[j] = (_Float16)(xv[br][v * 3 + 2] * g);
        }
      }
      *(half8*)&As[0][br * 64 + p * 8] = a0;
      *(half8*)&As[1][br * 64 + p * 8] = a1;
      *(half8*)&As[2][br * 64 + p * 8] = a2;
    }
    __syncthreads();
#pragma unroll
    for (int kk = 0; kk < 2; ++kk) {
      int q = kk * 4 + quad;
      half8 bf = *(const half8*)&w1oT[(size_t)(ct + m16) * M1P + k0 + kk * 32 + quad * 8];
#pragma unroll
      for (int i = 0; i < 3; ++i) {
        half8 af = *(const half8*)&As[i][(rt + m16) * 64 + (q ^ (m16 & 7)) * 8];
        acc[i] = __builtin_amdgcn_mfma_f32_16x16x32_f16(af, bf, acc[i], 0, 0, 0);
      }
    }
  }
#pragma unroll
  for (int i = 0; i < 3; ++i)
#pragma unroll
    for (int rr = 0; rr < 4; ++rr)
      out[(n0 + rt + quad * 4 + rr) * 288 + 64 + (ct + m16) * 3 + i] = acc[i][rr];
}

// ---------------------------------------------------------------------------
// epi1e2: blockIdx.y==0 -> o1e (K=496->512), ==1 -> o2 (K=528->544).
// ---------------------------------------------------------------------------
__global__ __launch_bounds__(256) void epi1e2_kernel(
    const float* __restrict__ xv_g, const _Float16* __restrict__ G,
    const _Float16* __restrict__ w1eT, const _Float16* __restrict__ w2eT,
    float* __restrict__ out) {
  __shared__ float xv[64][96];
  __shared__ alignas(16) _Float16 As[5][64 * 32];
  __shared__ uint8_t pa[544], pb[544];
  const int t = threadIdx.x;
  const size_t n0 = (size_t)blockIdx.x * 64;
  const int phase = blockIdx.y;
  for (int idx = t; idx < 64 * 96; idx += 256)
    xv[idx / 96][idx % 96] = xv_g[(n0 + idx / 96) * 96 + idx % 96];
  for (int p = t; p < 544; p += 256) {
    int a = 0, b = 0;
    if (phase == 0) {
      if (p < A1C) { triu_ab(p, 31, a, b); b += 1; }
    } else {
      if (p < P1C) triu_ab(p, 32, a, b);
    }
    pa[p] = (uint8_t)a; pb[p] = (uint8_t)b;
  }
  const int lane = t & 63, wave = t >> 6;
  const int m16 = lane & 15, quad = lane >> 4;
  const int sw8 = (quad ^ ((m16 >> 1) & 3)) * 8;
  const int br = t >> 2;
  const int bc8 = ((t & 3) ^ ((br >> 1) & 3)) * 8;  // swizzled source chunk
  const int lc8 = (t & 3) * 8;                      // LDS column
  const float s2 = 0.70710678118654752f, s6 = 0.40824829046386302f;
  __syncthreads();

  if (phase == 0) {  // ---- o1e: cross pairs ----
    floatx4 acc[3] = {};
    for (int k0 = 0; k0 < 512; k0 += 32) {
      if (k0) __syncthreads();
      {
        half8 g8 = *(const half8*)&G[(n0 + br) * NP2 + (M0C + M1C) + k0 + bc8];
        half8 a0, a1, a2;
#pragma unroll
        for (int j = 0; j < 8; ++j) {
          int p = k0 + bc8 + j;
          if (p < A1C) {
            int a = pa[p], b = pb[p];
            float ax = xv[br][a * 3], ay = xv[br][a * 3 + 1], az = xv[br][a * 3 + 2];
            float bx = xv[br][b * 3], by = xv[br][b * 3 + 1], bz = xv[br][b * 3 + 2];
            float g = (float)g8[j] * s2;
            a0[j] = (_Float16)((ay * bz - az * by) * g);
            a1[j] = (_Float16)((az * bx - ax * bz) * g);
            a2[j] = (_Float16)((ax * by - ay * bx) * g);
          } else {
            a0[j] = (_Float16)0.f; a1[j] = (_Float16)0.f; a2[j] = (_Float16)0.f;
          }
        }
        *(half8*)&As[0][br * 32 + lc8] = a0;
        *(half8*)&As[1][br * 32 + lc8] = a1;
        *(half8*)&As[2][br * 32 + lc8] = a2;
      }
      __syncthreads();
      half8 bf = *(const half8*)&w1eT[(size_t)m16 * 512 + k0 + quad * 8];
#pragma unroll
      for (int i = 0; i < 3; ++i) {
        half8 af = *(const half8*)&As[i][(wave * 16 + m16) * 32 + sw8];
        acc[i] = __builtin_amdgcn_mfma_f32_16x16x32_f16(af, bf, acc[i], 0, 0, 0);
      }
    }
#pragma unroll
    for (int i = 0; i < 3; ++i)
#pragma unroll
      for (int rr = 0; rr < 4; ++rr)
        out[(n0 + wave * 16 + quad * 4 + rr) * 288 + 160 + m16 * 3 + i] = acc[i][rr];
  } else {  // ---- o2: symmetric pairs ----
    floatx4 acc[5] = {};
    for (int k0 = 0; k0 < 544; k0 += 32) {
      if (k0) __syncthreads();
      {
        half8 g8 = *(const half8*)&G[(n0 + br) * NP2 + (M0C + M1C + A1C) + k0 + bc8];
        half8 m0v, m1v, m2v, m3v, m4v;
#pragma unroll
        for (int j = 0; j < 8; ++j) {
          int p = k0 + bc8 + j;
          if (p < P1C) {
            int a = pa[p], b = pb[p];
            float ax = xv[br][a * 3], ay = xv[br][a * 3 + 1], az = xv[br][a * 3 + 2];
            float bx = xv[br][b * 3], by = xv[br][b * 3 + 1], bz = xv[br][b * 3 + 2];
            float c1 = (a == b) ? s2 : 1.f;
            float gw = (float)g8[j] * c1;
            m0v[j] = (_Float16)(s2 * (ax * by + ay * bx) * gw);
            m1v[j] = (_Float16)(s2 * (ay * bz + az * by) * gw);
            m2v[j] = (_Float16)(s2 * (ax * bz + az * bx) * gw);
            m3v[j] = (_Float16)(s2 * (ax * bx - ay * by) * gw);
            m4v[j] = (_Float16)(s6 * (2.f * az * bz - ax * bx - ay * by) * gw);
          } else {
            m0v[j] = (_Float16)0.f; m1v[j] = (_Float16)0.f; m2v[j] = (_Float16)0.f;
            m3v[j] = (_Float16)0.f; m4v[j] = (_Float16)0.f;
          }
        }
        *(half8*)&As[0][br * 32 + lc8] = m0v;
        *(half8*)&As[1][br * 32 + lc8] = m1v;
        *(half8*)&As[2][br * 32 + lc8] = m2v;
        *(half8*)&As[3][br * 32 + lc8] = m3v;
        *(half8*)&As[4][br * 32 + lc8] = m4v;
      }
      __syncthreads();
      half8 bf = *(const half8*)&w2eT[(size_t)m16 * 544 + k0 + quad * 8];
#pragma unroll
      for (int m = 0; m < 5; ++m) {
        half8 af = *(const half8*)&As[m][(wave * 16 + m16) * 32 + sw8];
        acc[m] = __builtin_amdgcn_mfma_f32_16x16x32_f16(af, bf, acc[m], 0, 0, 0);
      }
    }
#pragma unroll
    for (int m = 0; m < 5; ++m)
#pragma unroll
      for (int rr = 0; rr < 4; ++rr)
        out[(n0 + wave * 16 + quad * 4 + rr) * 288 + 208 + m16 * 5 + m] = acc[m][rr];
  }
}

// ---------------------------------------------------------------------------
extern "C" void kernel_launch(void* const* d_in, const int* in_sizes, int n_in,
                              void* d_out, int out_size, void* d_ws, size_t ws_size,
                              hipStream_t stream) {
  const float* xs  = (const float*)d_in[0];
  const float* xv  = (const float*)d_in[1];
  const float* w1  = (const float*)d_in[2];
  const float* w2  = (const float*)d_in[3];
  const float* w0  = (const float*)d_in[4];
  const float* w1o = (const float*)d_in[5];
  const float* w1e = (const float*)d_in[6];
  const float* w2e = (const float*)d_in[7];
  float* out = (float*)d_out;

  char* ws = (char*)d_ws;
  size_t off = 0;
  _Float16* w1T = (_Float16*)(ws + off); off += (size_t)NPAD1 * KP * 2;    // 15.14 MB
  _Float16* w2T = (_Float16*)(ws + off); off += (size_t)NP2 * KP * 2;      // 31.65 MB
  _Float16* f0p = (_Float16*)(ws + off); off += (size_t)N_ROWS * KP * 2;   // 44.04 MB
  _Float16* H   = (_Float16*)(ws + off); off += (size_t)N_ROWS * NPAD1 * 2;// 46.14 MB
  _Float16* G   = (_Float16*)(ws + off);                                   // 96.47 MB
  // total ~233.4 MB

  // Small epilogue weights live inside w1T's region (dead after GEMM1).
  _Float16* w0T  = w1T;                                     // 64 x 2688 = 344064 B
  _Float16* w1oT = (_Float16*)((char*)w1T + 344064);        // 32 x 2112 = 135168 B
  _Float16* w1eT = (_Float16*)((char*)w1T + 479232);        // 32 x 512  =  32768 B
  _Float16* w2eT = (_Float16*)((char*)w1T + 512000);        // 32 x 544  =  34816 B

  transpose_cvt_kernel<<<dim3(KP / 32, NPAD1 / 32), 256, 0, stream>>>(w1, w1T, M0C, M0C, KP);
  transpose_cvt_kernel<<<dim3(KP / 32, NP2 / 32), 256, 0, stream>>>(w2, w2T, M0C, NIR, KP);
  build_f0_kernel<<<N_ROWS, 256, 0, stream>>>(xs, xv, f0p);
  gemm256_kernel<true><<<dim3(NPAD1 / 256, N_ROWS / 256), 512, 0, stream>>>(
      f0p, w1T, H, KP, KP, KP, NPAD1);
  // w1T now dead -> overwrite with epilogue weights
  transpose_cvt_kernel<<<dim3(KP / 32, 2), 256, 0, stream>>>(w0, w0T, M0C, 64, KP);
  transpose_cvt_kernel<<<dim3(M1P / 32, 1), 256, 0, stream>>>(w1o, w1oT, M1C, 32, M1P);
  transpose_cvt_kernel<<<dim3(16, 1), 256, 0, stream>>>(w1e, w1eT, A1C, 16, 512);
  transpose_cvt_kernel<<<dim3(17, 1), 256, 0, stream>>>(w2e, w2eT, P1C, 16, 544);
  gemm256_kernel<false><<<dim3(NP2 / 256, N_ROWS / 256), 512, 0, stream>>>(
      H, w2T, G, KP, NPAD1, KP, NP2);
  epi0_kernel<<<256, 256, 0, stream>>>(f0p, G, w0T, out);
  epi1_kernel<<<256, 256, 0, stream>>>(xs, xv, G, w1oT, out);
  epi1e2_kernel<<<dim3(128, 2), 256, 0, stream>>>(xv, G, w1eT, w2eT, out);
}

// Round 4
// 759.902 us; speedup vs baseline: 1.0781x; 1.0781x over previous
//
#include <hip/hip_runtime.h>
#include <hip/hip_bf16.h>
#include <stdint.h>

// Problem constants
#define N_ROWS 8192
#define M0C 2672    // C0 + P0 + P1 = 64 + 2080 + 528
#define M1C 2080    // C1 + C0*C1
#define A1C 496
#define P1C 528
#define KP  2688    // M0 padded to multiple of 128 (and 32 for BK)
#define NP2 5888    // NUM_IRREPS (5776) padded to multiple of 256
#define NIR 5776
#define M1P 2112    // M1C padded to multiple of 64
#define NPAD1 2816  // GEMM1 N (=M0) padded to multiple of 256 (11*256)

typedef __attribute__((ext_vector_type(8))) _Float16 half8;
typedef __attribute__((ext_vector_type(4))) float floatx4;

__device__ __forceinline__ void async_copy16(const _Float16* g, _Float16* l) {
  __builtin_amdgcn_global_load_lds(
      (__attribute__((address_space(1))) void*)(g),
      (__attribute__((address_space(3))) void*)(l), 16, 0, 0);
}

// ---------------------------------------------------------------------------
// Transpose + fp32->fp16 convert with zero padding.
// ---------------------------------------------------------------------------
__global__ __launch_bounds__(256) void transpose_cvt_kernel(
    const float* __restrict__ src, _Float16* __restrict__ dst,
    int srcR, int srcC, int dstC) {
  __shared__ float tile[32][33];
  const int t = threadIdx.x, tx = t & 31, ty = t >> 5;
  const int bx = blockIdx.x, by = blockIdx.y;
#pragma unroll
  for (int i = 0; i < 4; ++i) {
    int sr = bx * 32 + ty + i * 8;   // src row (k dim)
    int sc = by * 32 + tx;           // src col
    tile[ty + i * 8][tx] = (sr < srcR && sc < srcC) ? src[(size_t)sr * srcC + sc] : 0.f;
  }
  __syncthreads();
#pragma unroll
  for (int i = 0; i < 4; ++i) {
    int dr = by * 32 + ty + i * 8;
    int dc = bx * 32 + tx;
    dst[(size_t)dr * dstC + dc] = (_Float16)tile[tx][ty + i * 8];
  }
}

// ---------------------------------------------------------------------------
// triu_indices(C) pair decode: p -> (a, b), b >= a.
// ---------------------------------------------------------------------------
__device__ __forceinline__ void triu_ab(int p, int C, int& a, int& b) {
  float fC = (float)C + 0.5f;
  int ai = (int)(fC - sqrtf(fC * fC - 2.0f * (float)p));
  if (ai < 0) ai = 0;
  while (ai > 0 && ai * C - ai * (ai - 1) / 2 > p) --ai;
  while ((ai + 1) * C - (ai + 1) * ai / 2 <= p) ++ai;
  a = ai;
  b = p - (ai * C - ai * (ai - 1) / 2) + ai;
}

// ---------------------------------------------------------------------------
// f0 = [x_s (64) | ss (2080) | vv0 (528) | zero pad (16)]  as fp16 [N][KP]
// ---------------------------------------------------------------------------
__global__ __launch_bounds__(256) void build_f0_kernel(
    const float* __restrict__ xs_g, const float* __restrict__ xv_g,
    _Float16* __restrict__ f0p) {
  __shared__ float xs[64];
  __shared__ float xv[96];
  const int t = threadIdx.x;
  const size_t n = blockIdx.x;
  if (t < 64) xs[t] = xs_g[n * 64 + t];
  else if (t < 160) xv[t - 64] = xv_g[n * 96 + (t - 64)];
  __syncthreads();
  for (int c = t; c < KP; c += 256) {
    float v;
    if (c < 64) {
      v = xs[c];
    } else if (c < 2144) {                       // ss: pair products of x_s
      int a, b;
      triu_ab(c - 64, 64, a, b);
      v = xs[a] * xs[b] * ((a == b) ? 0.70710678118654752f : 1.f);
    } else if (c < M0C) {                        // vv0: pair dots of x_v
      int a, b;
      triu_ab(c - 2144, 32, a, b);
      float d = xv[a * 3] * xv[b * 3] + xv[a * 3 + 1] * xv[b * 3 + 1] +
                xv[a * 3 + 2] * xv[b * 3 + 2];
      v = d * ((a == b) ? 0.70710678118654752f : 1.f) * 0.57735026918962576f;
    } else {
      v = 0.f;                                   // pad
    }
    f0p[n * KP + c] = (_Float16)v;
  }
}

// ---------------------------------------------------------------------------
// fp16 MFMA GEMM, 256x256 tile, BK=32, 8 waves (wave tile 128x64).
// Round-3: m201-style 8-phase schedule. Each 32-K-tile = 2 phases (row-half
// h): {ds_read this phase's frags; stage one half of tile t+2 (A at h=0,
// B at h=1); counted vmcnt (h=1 only, confirms slot t+1); barrier;
// lgkmcnt(0); setprio(1) 16 MFMA setprio(0); barrier}.  4-slot LDS ring
// (As 64 KiB + Bs 64 KiB).  vmcnt(4) steady state (= A(t+2)+B(t+2) in
// flight), never 0 in the main loop; tail 4 -> 4 -> 0.
// Race-freedom: slot t confirmed by vmcnt(4)+barrier at phase (t-1,1),
// one phase before its first ds_read; slot t+2's last readers (tile t-2)
// drained >=2 barriers before its restage at (t,0).
// B stored transposed [N][K]. Requires K % 128 == 0.
// ---------------------------------------------------------------------------
template <bool SILU>
__global__ __launch_bounds__(512, 2) void gemm256_kernel(
    const _Float16* __restrict__ A, const _Float16* __restrict__ B,
    _Float16* __restrict__ C, int K, int lda, int ldb, int ldc) {
  __shared__ alignas(16) _Float16 As[4 * 8192];
  __shared__ alignas(16) _Float16 Bs[4 * 8192];
  const int tid = threadIdx.x;

  // XCD-aware bijective remap. 32 row-tiles / 8 XCDs = 4 row-tiles per XCD;
  // sweep cols with 2-row-tile sub-bands so the A sub-band stays L2-resident
  // and B col-tiles are shared by 2 concurrent row-blocks.
  const int ncol = gridDim.x;
  const int id = blockIdx.y * ncol + blockIdx.x;
  const int xcd = id & 7;
  const int j = id >> 3;              // [0, 4*ncol)
  const int hb = j / (2 * ncol);      // 0..1
  const int w = j - hb * 2 * ncol;    // [0, 2*ncol)
  const int by = xcd * 4 + hb * 2 + (w & 1);
  const int bx = w >> 1;
  const size_t row0 = (size_t)by * 256;
  const size_t col0 = (size_t)bx * 256;

  // Staging: 2 chunks of A + 2 chunks of B per thread per K-tile (16 B each).
  // LDS dest stays lane-contiguous; the XOR swizzle is applied to the global
  // SOURCE chunk (both-sides-or-neither rule).
  const _Float16 *pA0, *pA1, *pB0, *pB1;
  _Float16 *lA0, *lA1, *lB0, *lB1;
  {
    int c0 = tid, c1 = tid + 512;
    int r0 = c0 >> 2, ch0 = c0 & 3;
    int r1 = c1 >> 2, ch1 = c1 & 3;
    int s0 = ch0 ^ ((r0 >> 1) & 3);
    int s1 = ch1 ^ ((r1 >> 1) & 3);
    pA0 = A + (row0 + r0) * lda + s0 * 8;
    pA1 = A + (row0 + r1) * lda + s1 * 8;
    pB0 = B + (col0 + r0) * ldb + s0 * 8;
    pB1 = B + (col0 + r1) * ldb + s1 * 8;
    lA0 = &As[c0 * 8]; lA1 = &As[c1 * 8];
    lB0 = &Bs[c0 * 8]; lB1 = &Bs[c1 * 8];
  }

  const int lane = tid & 63;
  const int wv = tid >> 6;       // 0..7
  const int wm = wv & 1;         // M half (128 rows)
  const int wn = wv >> 1;        // N quarter (64 cols)
  const int m16 = lane & 15;
  const int quad = lane >> 4;
  const int sw8 = (quad ^ ((m16 >> 1) & 3)) * 8;   // swizzled read chunk
  const int aoff = (wm * 128 + m16) * 32 + sw8;    // + ii*512
  const int boff = (wn * 64 + m16) * 32 + sw8;     // + jj*512

  floatx4 acc[8][4] = {};
  half8 af[4], bf[4];

#define STAGE_A(SLOT)                                 \
  {                                                   \
    async_copy16(pA0, lA0 + (SLOT) * 8192);           \
    async_copy16(pA1, lA1 + (SLOT) * 8192);           \
    pA0 += 32; pA1 += 32;                             \
  }
#define STAGE_B(SLOT)                                 \
  {                                                   \
    async_copy16(pB0, lB0 + (SLOT) * 8192);           \
    async_copy16(pB1, lB1 + (SLOT) * 8192);           \
    pB0 += 32; pB1 += 32;                             \
  }

  // Phase h=0 of tile in slot BB: read A-frags ii=0..3 + all B-frags,
  // stage A(t+2); no vmcnt. MFMA quadrant acc[0..3][*].
#define PH0(BB, DO_STAGE)                                                     \
  {                                                                           \
    _Pragma("unroll")                                                         \
    for (int ii = 0; ii < 4; ++ii)                                            \
      af[ii] = *(const half8*)&As[(BB) * 8192 + aoff + ii * 512];             \
    _Pragma("unroll")                                                         \
    for (int jj = 0; jj < 4; ++jj)                                            \
      bf[jj] = *(const half8*)&Bs[(BB) * 8192 + boff + jj * 512];             \
    if (DO_STAGE) STAGE_A(((BB) + 2) & 3);                                    \
    __builtin_amdgcn_sched_barrier(0);                                        \
    __builtin_amdgcn_s_barrier();                                             \
    asm volatile("s_waitcnt lgkmcnt(0)" ::: "memory");                        \
    __builtin_amdgcn_sched_barrier(0);                                        \
    __builtin_amdgcn_s_setprio(1);                                            \
    _Pragma("unroll")                                                         \
    for (int ii = 0; ii < 4; ++ii)                                            \
      _Pragma("unroll")                                                       \
      for (int jj = 0; jj < 4; ++jj)                                          \
        acc[ii][jj] = __builtin_amdgcn_mfma_f32_16x16x32_f16(                 \
            af[ii], bf[jj], acc[ii][jj], 0, 0, 0);                            \
    __builtin_amdgcn_s_setprio(0);                                            \
    __builtin_amdgcn_sched_barrier(0);                                        \
    __builtin_amdgcn_s_barrier();                                             \
  }

  // Phase h=1 of tile in slot BB: read A-frags ii=4..7 (bf persists from
  // h=0), stage B(t+2), counted vmcnt confirming slot t+1. acc[4..7][*].
#define PH1(BB, DO_STAGE, VMLIT)                                              \
  {                                                                           \
    _Pragma("unroll")                                                         \
    for (int ii = 0; ii < 4; ++ii)                                            \
      af[ii] = *(const half8*)&As[(BB) * 8192 + aoff + (ii + 4) * 512];       \
    if (DO_STAGE) STAGE_B(((BB) + 2) & 3);                                    \
    asm volatile("s_waitcnt vmcnt(" VMLIT ")" ::: "memory");                  \
    __builtin_amdgcn_sched_barrier(0);                                        \
    __builtin_amdgcn_s_barrier();                                             \
    asm volatile("s_waitcnt lgkmcnt(0)" ::: "memory");                        \
    __builtin_amdgcn_sched_barrier(0);                                        \
    __builtin_amdgcn_s_setprio(1);                                            \
    _Pragma("unroll")                                                         \
    for (int ii = 0; ii < 4; ++ii)                                            \
      _Pragma("unroll")                                                       \
      for (int jj = 0; jj < 4; ++jj)                                          \
        acc[ii + 4][jj] = __builtin_amdgcn_mfma_f32_16x16x32_f16(             \
            af[ii], bf[jj], acc[ii + 4][jj], 0, 0, 0);                        \
    __builtin_amdgcn_s_setprio(0);                                            \
    __builtin_amdgcn_sched_barrier(0);                                        \
    __builtin_amdgcn_s_barrier();                                             \
  }

  // Prologue: stage tiles 0 and 1; confirm slot 0 (leave A(1),B(1) in flight).
  STAGE_A(0); STAGE_B(0);
  STAGE_A(1); STAGE_B(1);
  asm volatile("s_waitcnt vmcnt(4)" ::: "memory");
  __builtin_amdgcn_s_barrier();

  const int T = K >> 5;               // 84 for K=2688 (divisible by 4)
  for (int t4 = 0; t4 < T - 4; t4 += 4) {
    PH0(0, 1); PH1(0, 1, "4");
    PH0(1, 1); PH1(1, 1, "4");
    PH0(2, 1); PH1(2, 1, "4");
    PH0(3, 1); PH1(3, 1, "4");
  }
  // Tail: tiles T-4 .. T-1 (slots 0..3). T-4 stages T-2; T-3 stages T-1.
  PH0(0, 1); PH1(0, 1, "4");
  PH0(1, 1); PH1(1, 1, "4");
  PH0(2, 0); PH1(2, 0, "0");
  PH0(3, 0); PH1(3, 0, "0");
#undef PH1
#undef PH0
#undef STAGE_B
#undef STAGE_A

  // C/D layout: col = lane&15, row = quad*4 + reg
#pragma unroll
  for (int ii = 0; ii < 8; ++ii) {
    size_t r = row0 + wm * 128 + ii * 16 + quad * 4;
#pragma unroll
    for (int jj = 0; jj < 4; ++jj) {
      size_t cc = col0 + wn * 64 + jj * 16 + m16;
#pragma unroll
      for (int rr = 0; rr < 4; ++rr) {
        float v = acc[ii][jj][rr];
        if (SILU) v = v / (1.f + __expf(-v));
        C[(r + rr) * ldc + cc] = (_Float16)v;
      }
    }
  }
}

// ---------------------------------------------------------------------------
// epi0: o0 = (f0 .* g0) @ w0.  32 rows/block, BK=64, K=2688, N=64. grid 256.
// ---------------------------------------------------------------------------
__global__ __launch_bounds__(256) void epi0_kernel(
    const _Float16* __restrict__ f0p, const _Float16* __restrict__ G,
    const _Float16* __restrict__ w0T, float* __restrict__ out) {
  __shared__ alignas(16) _Float16 As[32 * 64];
  const int t = threadIdx.x;
  const size_t n0 = (size_t)blockIdx.x * 32;
  const int lane = t & 63, wave = t >> 6;
  const int m16 = lane & 15, quad = lane >> 4;
  const int rt = (wave & 1) * 16;        // row tile base
  const int ctb = (wave >> 1) * 32;      // col pair base
  const int br = t >> 3, p = t & 7;      // build: row, physical chunk
  const int l8 = (p ^ (br & 7)) * 8;     // logical k offset

  floatx4 acc[2] = {};
  for (int k0 = 0; k0 < KP; k0 += 64) {
    if (k0) __syncthreads();
    {
      half8 f = *(const half8*)&f0p[(n0 + br) * KP + k0 + l8];
      half8 g = *(const half8*)&G[(n0 + br) * NP2 + k0 + l8];
      half8 a;
#pragma unroll
      for (int j = 0; j < 8; ++j) a[j] = (_Float16)((float)f[j] * (float)g[j]);
      *(half8*)&As[br * 64 + p * 8] = a;
    }
    __syncthreads();
#pragma unroll
    for (int kk = 0; kk < 2; ++kk) {
      int q = kk * 4 + quad;
      half8 af = *(const half8*)&As[(rt + m16) * 64 + (q ^ (m16 & 7)) * 8];
#pragma unroll
      for (int c = 0; c < 2; ++c) {
        half8 bf = *(const half8*)&w0T[(size_t)(ctb + c * 16 + m16) * KP + k0 + kk * 32 + quad * 8];
        acc[c] = __builtin_amdgcn_mfma_f32_16x16x32_f16(af, bf, acc[c], 0, 0, 0);
      }
    }
  }
#pragma unroll
  for (int c = 0; c < 2; ++c)
#pragma unroll
    for (int rr = 0; rr < 4; ++rr)
      out[(n0 + rt + quad * 4 + rr) * 288 + ctb + c * 16 + m16] = acc[c][rr];
}

// ---------------------------------------------------------------------------
// epi1: o1[n][o][i] = sum_c f1[n][c][i]*g1[n][c]*w1o[c][o].
// ---------------------------------------------------------------------------
__global__ __launch_bounds__(256) void epi1_kernel(
    const float* __restrict__ xs_g, const float* __restrict__ xv_g,
    const _Float16* __restrict__ G, const _Float16* __restrict__ w1oT,
    float* __restrict__ out) {
  __shared__ float xs[32][64];
  __shared__ float xv[32][96];
  __shared__ alignas(16) _Float16 As[3][32 * 64];
  const int t = threadIdx.x;
  const size_t n0 = (size_t)blockIdx.x * 32;
  for (int idx = t; idx < 32 * 64; idx += 256)
    xs[idx >> 6][idx & 63] = xs_g[(n0 + (idx >> 6)) * 64 + (idx & 63)];
  for (int idx = t; idx < 32 * 96; idx += 256)
    xv[idx / 96][idx % 96] = xv_g[(n0 + idx / 96) * 96 + idx % 96];
  const int lane = t & 63, wave = t >> 6;
  const int m16 = lane & 15, quad = lane >> 4;
  const int rt = (wave & 1) * 16;   // row tile
  const int ct = (wave >> 1) * 16;  // col tile
  const int br = t >> 3, p = t & 7;
  const int l8 = (p ^ (br & 7)) * 8;

  floatx4 acc[3] = {};
  __syncthreads();
  for (int k0 = 0; k0 < M1P; k0 += 64) {
    if (k0) __syncthreads();
    {
      half8 g8 = *(const half8*)&G[(n0 + br) * NP2 + M0C + k0 + l8];
      int kbase = k0 + l8;
      half8 a0, a1, a2;
      if (kbase < 32) {
#pragma unroll
        for (int j = 0; j < 8; ++j) {
          float g = (float)g8[j];
          int v = kbase + j;
          a0[j] = (_Float16)(xv[br][v * 3 + 0] * g);
          a1[j] = (_Float16)(xv[br][v * 3 + 1] * g);
          a2[j] = (_Float16)(xv[br][v * 3 + 2] * g);
        }
      } else {
        int s = (kbase - 32) >> 5;
        if (s > 63) s = 63;                  // pad region: B is zero anyway
        int v0 = (kbase - 32) & 31;
        float xsr = xs[br][s];
#pragma unroll
        for (int j = 0; j < 8; ++j) {
          float g = (float)g8[j] * xsr;
          int v = v0 + j;
          a0[j] = (_Float16)(xv[br][v * 3 + 0] * g);
          a1[j] = (_Float16)(xv[br][v * 3 + 1] * g);
          a2[j] = (_Float16)(xv[br][v * 3 + 2] * g);
        }
      }
      *(half8*)&As[0][br * 64 + p * 8] = a0;
      *(half8*)&As[1][br * 64 + p * 8] = a1;
      *(half8*)&As[2][br * 64 + p * 8] = a2;
    }
    __syncthreads();
#pragma unroll
    for (int kk = 0; kk < 2; ++kk) {
      int q = kk * 4 + quad;
      half8 bf = *(const half8*)&w1oT[(size_t)(ct + m16) * M1P + k0 + kk * 32 + quad * 8];
#pragma unroll
      for (int i = 0; i < 3; ++i) {
        half8 af = *(const half8*)&As[i][(rt + m16) * 64 + (q ^ (m16 & 7)) * 8];
        acc[i] = __builtin_amdgcn_mfma_f32_16x16x32_f16(af, bf, acc[i], 0, 0, 0);
      }
    }
  }
#pragma unroll
  for (int i = 0; i < 3; ++i)
#pragma unroll
    for (int rr = 0; rr < 4; ++rr)
      out[(n0 + rt + quad * 4 + rr) * 288 + 64 + (ct + m16) * 3 + i] = acc[i][rr];
}

// ---------------------------------------------------------------------------
// epi1e2: blockIdx.y==0 -> o1e (K=496->512), ==1 -> o2 (K=528->544).
// ---------------------------------------------------------------------------
__global__ __launch_bounds__(256) void epi1e2_kernel(
    const float* __restrict__ xv_g, const _Float16* __restrict__ G,
    const _Float16* __restrict__ w1eT, const _Float16* __restrict__ w2eT,
    float* __restrict__ out) {
  __shared__ float xv[64][96];
  __shared__ alignas(16) _Float16 As[5][64 * 32];
  __shared__ uint8_t pa[544], pb[544];
  const int t = threadIdx.x;
  const size_t n0 = (size_t)blockIdx.x * 64;
  const int phase = blockIdx.y;
  for (int idx = t; idx < 64 * 96; idx += 256)
    xv[idx / 96][idx % 96] = xv_g[(n0 + idx / 96) * 96 + idx % 96];
  for (int p = t; p < 544; p += 256) {
    int a = 0, b = 0;
    if (phase == 0) {
      if (p < A1C) { triu_ab(p, 31, a, b); b += 1; }
    } else {
      if (p < P1C) triu_ab(p, 32, a, b);
    }
    pa[p] = (uint8_t)a; pb[p] = (uint8_t)b;
  }
  const int lane = t & 63, wave = t >> 6;
  const int m16 = lane & 15, quad = lane >> 4;
  const int sw8 = (quad ^ ((m16 >> 1) & 3)) * 8;
  const int br = t >> 2;
  const int bc8 = ((t & 3) ^ ((br >> 1) & 3)) * 8;  // swizzled source chunk
  const int lc8 = (t & 3) * 8;                      // LDS column
  const float s2 = 0.70710678118654752f, s6 = 0.40824829046386302f;
  __syncthreads();

  if (phase == 0) {  // ---- o1e: cross pairs ----
    floatx4 acc[3] = {};
    for (int k0 = 0; k0 < 512; k0 += 32) {
      if (k0) __syncthreads();
      {
        half8 g8 = *(const half8*)&G[(n0 + br) * NP2 + (M0C + M1C) + k0 + bc8];
        half8 a0, a1, a2;
#pragma unroll
        for (int j = 0; j < 8; ++j) {
          int p = k0 + bc8 + j;
          if (p < A1C) {
            int a = pa[p], b = pb[p];
            float ax = xv[br][a * 3], ay = xv[br][a * 3 + 1], az = xv[br][a * 3 + 2];
            float bx = xv[br][b * 3], by = xv[br][b * 3 + 1], bz = xv[br][b * 3 + 2];
            float g = (float)g8[j] * s2;
            a0[j] = (_Float16)((ay * bz - az * by) * g);
            a1[j] = (_Float16)((az * bx - ax * bz) * g);
            a2[j] = (_Float16)((ax * by - ay * bx) * g);
          } else {
            a0[j] = (_Float16)0.f; a1[j] = (_Float16)0.f; a2[j] = (_Float16)0.f;
          }
        }
        *(half8*)&As[0][br * 32 + lc8] = a0;
        *(half8*)&As[1][br * 32 + lc8] = a1;
        *(half8*)&As[2][br * 32 + lc8] = a2;
      }
      __syncthreads();
      half8 bf = *(const half8*)&w1eT[(size_t)m16 * 512 + k0 + quad * 8];
#pragma unroll
      for (int i = 0; i < 3; ++i) {
        half8 af = *(const half8*)&As[i][(wave * 16 + m16) * 32 + sw8];
        acc[i] = __builtin_amdgcn_mfma_f32_16x16x32_f16(af, bf, acc[i], 0, 0, 0);
      }
    }
#pragma unroll
    for (int i = 0; i < 3; ++i)
#pragma unroll
      for (int rr = 0; rr < 4; ++rr)
        out[(n0 + wave * 16 + quad * 4 + rr) * 288 + 160 + m16 * 3 + i] = acc[i][rr];
  } else {  // ---- o2: symmetric pairs ----
    floatx4 acc[5] = {};
    for (int k0 = 0; k0 < 544; k0 += 32) {
      if (k0) __syncthreads();
      {
        half8 g8 = *(const half8*)&G[(n0 + br) * NP2 + (M0C + M1C + A1C) + k0 + bc8];
        half8 m0v, m1v, m2v, m3v, m4v;
#pragma unroll
        for (int j = 0; j < 8; ++j) {
          int p = k0 + bc8 + j;
          if (p < P1C) {
            int a = pa[p], b = pb[p];
            float ax = xv[br][a * 3], ay = xv[br][a * 3 + 1], az = xv[br][a * 3 + 2];
            float bx = xv[br][b * 3], by = xv[br][b * 3 + 1], bz = xv[br][b * 3 + 2];
            float c1 = (a == b) ? s2 : 1.f;
            float gw = (float)g8[j] * c1;
            m0v[j] = (_Float16)(s2 * (ax * by + ay * bx) * gw);
            m1v[j] = (_Float16)(s2 * (ay * bz + az * by) * gw);
            m2v[j] = (_Float16)(s2 * (ax * bz + az * bx) * gw);
            m3v[j] = (_Float16)(s2 * (ax * bx - ay * by) * gw);
            m4v[j] = (_Float16)(s6 * (2.f * az * bz - ax * bx - ay * by) * gw);
          } else {
            m0v[j] = (_Float16)0.f; m1v[j] = (_Float16)0.f; m2v[j] = (_Float16)0.f;
            m3v[j] = (_Float16)0.f; m4v[j] = (_Float16)0.f;
          }
        }
        *(half8*)&As[0][br * 32 + lc8] = m0v;
        *(half8*)&As[1][br * 32 + lc8] = m1v;
        *(half8*)&As[2][br * 32 + lc8] = m2v;
        *(half8*)&As[3][br * 32 + lc8] = m3v;
        *(half8*)&As[4][br * 32 + lc8] = m4v;
      }
      __syncthreads();
      half8 bf = *(const half8*)&w2eT[(size_t)m16 * 544 + k0 + quad * 8];
#pragma unroll
      for (int m = 0; m < 5; ++m) {
        half8 af = *(const half8*)&As[m][(wave * 16 + m16) * 32 + sw8];
        acc[m] = __builtin_amdgcn_mfma_f32_16x16x32_f16(af, bf, acc[m], 0, 0, 0);
      }
    }
#pragma unroll
    for (int m = 0; m < 5; ++m)
#pragma unroll
      for (int rr = 0; rr < 4; ++rr)
        out[(n0 + wave * 16 + quad * 4 + rr) * 288 + 208 + m16 * 5 + m] = acc[m][rr];
  }
}

// ---------------------------------------------------------------------------
extern "C" void kernel_launch(void* const* d_in, const int* in_sizes, int n_in,
                              void* d_out, int out_size, void* d_ws, size_t ws_size,
                              hipStream_t stream) {
  const float* xs  = (const float*)d_in[0];
  const float* xv  = (const float*)d_in[1];
  const float* w1  = (const float*)d_in[2];
  const float* w2  = (const float*)d_in[3];
  const float* w0  = (const float*)d_in[4];
  const float* w1o = (const float*)d_in[5];
  const float* w1e = (const float*)d_in[6];
  const float* w2e = (const float*)d_in[7];
  float* out = (float*)d_out;

  char* ws = (char*)d_ws;
  size_t off = 0;
  _Float16* w1T = (_Float16*)(ws + off); off += (size_t)NPAD1 * KP * 2;    // 15.14 MB
  _Float16* w2T = (_Float16*)(ws + off); off += (size_t)NP2 * KP * 2;      // 31.65 MB
  _Float16* f0p = (_Float16*)(ws + off); off += (size_t)N_ROWS * KP * 2;   // 44.04 MB
  _Float16* H   = (_Float16*)(ws + off); off += (size_t)N_ROWS * NPAD1 * 2;// 46.14 MB
  _Float16* G   = (_Float16*)(ws + off);                                   // 96.47 MB
  // total ~233.4 MB

  // Small epilogue weights live inside w1T's region (dead after GEMM1).
  _Float16* w0T  = w1T;                                     // 64 x 2688 = 344064 B
  _Float16* w1oT = (_Float16*)((char*)w1T + 344064);        // 32 x 2112 = 135168 B
  _Float16* w1eT = (_Float16*)((char*)w1T + 479232);        // 32 x 512  =  32768 B
  _Float16* w2eT = (_Float16*)((char*)w1T + 512000);        // 32 x 544  =  34816 B

  transpose_cvt_kernel<<<dim3(KP / 32, NPAD1 / 32), 256, 0, stream>>>(w1, w1T, M0C, M0C, KP);
  transpose_cvt_kernel<<<dim3(KP / 32, NP2 / 32), 256, 0, stream>>>(w2, w2T, M0C, NIR, KP);
  build_f0_kernel<<<N_ROWS, 256, 0, stream>>>(xs, xv, f0p);
  gemm256_kernel<true><<<dim3(NPAD1 / 256, N_ROWS / 256), 512, 0, stream>>>(
      f0p, w1T, H, KP, KP, KP, NPAD1);
  // w1T now dead -> overwrite with epilogue weights
  transpose_cvt_kernel<<<dim3(KP / 32, 2), 256, 0, stream>>>(w0, w0T, M0C, 64, KP);
  transpose_cvt_kernel<<<dim3(M1P / 32, 1), 256, 0, stream>>>(w1o, w1oT, M1C, 32, M1P);
  transpose_cvt_kernel<<<dim3(16, 1), 256, 0, stream>>>(w1e, w1eT, A1C, 16, 512);
  transpose_cvt_kernel<<<dim3(17, 1), 256, 0, stream>>>(w2e, w2eT, P1C, 16, 544);
  gemm256_kernel<false><<<dim3(NP2 / 256, N_ROWS / 256), 512, 0, stream>>>(
      H, w2T, G, KP, NPAD1, KP, NP2);
  epi0_kernel<<<256, 256, 0, stream>>>(f0p, G, w0T, out);
  epi1_kernel<<<256, 256, 0, stream>>>(xs, xv, G, w1oT, out);
  epi1e2_kernel<<<dim3(128, 2), 256, 0, stream>>>(xv, G, w1eT, w2eT, out);
}

// Round 7
// 751.023 us; speedup vs baseline: 1.0909x; 1.0118x over previous
//
#include <hip/hip_runtime.h>
#include <hip/hip_bf16.h>
#include <stdint.h>

// Problem constants
#define N_ROWS 8192
#define M0C 2672    // C0 + P0 + P1 = 64 + 2080 + 528
#define M1C 2080    // C1 + C0*C1
#define A1C 496
#define P1C 528
#define KP  2688    // M0 padded to multiple of 128 (and 32 for BK)
#define NP2 5888    // NUM_IRREPS (5776) padded to multiple of 256
#define NIR 5776
#define M1P 2112    // M1C padded to multiple of 64
#define NPAD1 2816  // GEMM1 N (=M0) padded to multiple of 256 (11*256)

typedef __attribute__((ext_vector_type(8))) _Float16 half8;
typedef __attribute__((ext_vector_type(4))) float floatx4;

__device__ __forceinline__ void async_copy16(const _Float16* g, _Float16* l) {
  __builtin_amdgcn_global_load_lds(
      (__attribute__((address_space(1))) void*)(g),
      (__attribute__((address_space(3))) void*)(l), 16, 0, 0);
}

// ---------------------------------------------------------------------------
// Transpose + fp32->fp16 convert with zero padding.  (round-2 verbatim)
// ---------------------------------------------------------------------------
__global__ __launch_bounds__(256) void transpose_cvt_kernel(
    const float* __restrict__ src, _Float16* __restrict__ dst,
    int srcR, int srcC, int dstC) {
  __shared__ float tile[32][33];
  const int t = threadIdx.x, tx = t & 31, ty = t >> 5;
  const int bx = blockIdx.x, by = blockIdx.y;
#pragma unroll
  for (int i = 0; i < 4; ++i) {
    int sr = bx * 32 + ty + i * 8;   // src row (k dim)
    int sc = by * 32 + tx;           // src col
    tile[ty + i * 8][tx] = (sr < srcR && sc < srcC) ? src[(size_t)sr * srcC + sc] : 0.f;
  }
  __syncthreads();
#pragma unroll
  for (int i = 0; i < 4; ++i) {
    int dr = by * 32 + ty + i * 8;
    int dc = bx * 32 + tx;
    dst[(size_t)dr * dstC + dc] = (_Float16)tile[tx][ty + i * 8];
  }
}

// ---------------------------------------------------------------------------
// triu_indices(C) pair decode: p -> (a, b), b >= a.
// ---------------------------------------------------------------------------
__device__ __forceinline__ void triu_ab(int p, int C, int& a, int& b) {
  float fC = (float)C + 0.5f;
  int ai = (int)(fC - sqrtf(fC * fC - 2.0f * (float)p));
  if (ai < 0) ai = 0;
  while (ai > 0 && ai * C - ai * (ai - 1) / 2 > p) --ai;
  while ((ai + 1) * C - (ai + 1) * ai / 2 <= p) ++ai;
  a = ai;
  b = p - (ai * C - ai * (ai - 1) / 2) + ai;
}

// ---------------------------------------------------------------------------
// f0 = [x_s (64) | ss (2080) | vv0 (528) | zero pad (16)]  as fp16 [N][KP]
// (round-2 verbatim)
// ---------------------------------------------------------------------------
__global__ __launch_bounds__(256) void build_f0_kernel(
    const float* __restrict__ xs_g, const float* __restrict__ xv_g,
    _Float16* __restrict__ f0p) {
  __shared__ float xs[64];
  __shared__ float xv[96];
  const int t = threadIdx.x;
  const size_t n = blockIdx.x;
  if (t < 64) xs[t] = xs_g[n * 64 + t];
  else if (t < 160) xv[t - 64] = xv_g[n * 96 + (t - 64)];
  __syncthreads();
  for (int c = t; c < KP; c += 256) {
    float v;
    if (c < 64) {
      v = xs[c];
    } else if (c < 2144) {                       // ss: pair products of x_s
      int a, b;
      triu_ab(c - 64, 64, a, b);
      v = xs[a] * xs[b] * ((a == b) ? 0.70710678118654752f : 1.f);
    } else if (c < M0C) {                        // vv0: pair dots of x_v
      int a, b;
      triu_ab(c - 2144, 32, a, b);
      float d = xv[a * 3] * xv[b * 3] + xv[a * 3 + 1] * xv[b * 3 + 1] +
                xv[a * 3 + 2] * xv[b * 3 + 2];
      v = d * ((a == b) ? 0.70710678118654752f : 1.f) * 0.57735026918962576f;
    } else {
      v = 0.f;                                   // pad
    }
    f0p[n * KP + c] = (_Float16)v;
  }
}

// ---------------------------------------------------------------------------
// fp16 MFMA GEMM, 256x256 tile, BK=32, 8 waves (wave tile 128x64).
// Race-fixed schedule (round-5): {vmcnt(4); barrier; STAGE slot (t+3)&3;
// ds_reads (aHi of tile t, next-tile aLo/bF); MFMAs; lgkmcnt(0)}.
// Every wave's reads of a slot are lgkm-drained before its next barrier and
// the overwrite of that slot is issued after that barrier -> race-free.
// vmcnt(4) before the barrier confirms tile t+1 landed (outstanding =
// tiles t+1,t+2 = 8 loads).  Tail: 4,4,0,0.
// B stored transposed [N][K]. Requires K % 128 == 0.
// ---------------------------------------------------------------------------
template <bool SILU>
__global__ __launch_bounds__(512, 2) void gemm256_kernel(
    const _Float16* __restrict__ A, const _Float16* __restrict__ B,
    _Float16* __restrict__ C, int K, int lda, int ldb, int ldc) {
  __shared__ alignas(16) _Float16 As[4 * 8192];
  __shared__ alignas(16) _Float16 Bs[4 * 8192];
  const int tid = threadIdx.x;

  // XCD-aware bijective remap.
  const int ncol = gridDim.x;
  const int id = blockIdx.y * ncol + blockIdx.x;
  const int xcd = id & 7;
  const int j = id >> 3;
  const int hb = j / (2 * ncol);
  const int w = j - hb * 2 * ncol;
  const int by = xcd * 4 + hb * 2 + (w & 1);
  const int bx = w >> 1;
  const size_t row0 = (size_t)by * 256;
  const size_t col0 = (size_t)bx * 256;

  const _Float16 *pA0, *pA1, *pB0, *pB1;
  _Float16 *lA0, *lA1, *lB0, *lB1;
  {
    int c0 = tid, c1 = tid + 512;
    int r0 = c0 >> 2, ch0 = c0 & 3;
    int r1 = c1 >> 2, ch1 = c1 & 3;
    int s0 = ch0 ^ ((r0 >> 1) & 3);
    int s1 = ch1 ^ ((r1 >> 1) & 3);
    pA0 = A + (row0 + r0) * lda + s0 * 8;
    pA1 = A + (row0 + r1) * lda + s1 * 8;
    pB0 = B + (col0 + r0) * ldb + s0 * 8;
    pB1 = B + (col0 + r1) * ldb + s1 * 8;
    lA0 = &As[c0 * 8]; lA1 = &As[c1 * 8];
    lB0 = &Bs[c0 * 8]; lB1 = &Bs[c1 * 8];
  }

  const int lane = tid & 63;
  const int wv = tid >> 6;
  const int wm = wv & 1;
  const int wn = wv >> 1;
  const int m16 = lane & 15;
  const int quad = lane >> 4;
  const int sw8 = (quad ^ ((m16 >> 1) & 3)) * 8;
  const int aoff = (wm * 128 + m16) * 32 + sw8;
  const int boff = (wn * 64 + m16) * 32 + sw8;

  floatx4 acc[8][4] = {};

#define STAGE(BB)                                             \
  {                                                           \
    async_copy16(pA0, lA0 + (BB) * 8192);                     \
    async_copy16(pA1, lA1 + (BB) * 8192);                     \
    async_copy16(pB0, lB0 + (BB) * 8192);                     \
    async_copy16(pB1, lB1 + (BB) * 8192);                     \
    pA0 += 32; pA1 += 32; pB0 += 32; pB1 += 32;               \
  }

#define KITER(BB, CAA, CBF, CAB, NAA, NBF, VMLIT, DO_STAGE, DO_READN)         \
  {                                                                           \
    asm volatile("s_waitcnt vmcnt(" VMLIT ")" ::: "memory");                  \
    __builtin_amdgcn_s_barrier();                                             \
    __builtin_amdgcn_sched_barrier(0);                                        \
    if (DO_STAGE) STAGE(((BB) + 3) & 3);                                      \
    _Pragma("unroll")                                                         \
    for (int ii = 0; ii < 4; ++ii)                                            \
      CAB[ii] = *(const half8*)&As[(BB) * 8192 + aoff + (ii + 4) * 512];      \
    if (DO_READN) {                                                           \
      _Pragma("unroll")                                                       \
      for (int jj = 0; jj < 4; ++jj)                                          \
        NBF[jj] = *(const half8*)&Bs[(((BB) + 1) & 3) * 8192 + boff + jj * 512]; \
      _Pragma("unroll")                                                       \
      for (int ii = 0; ii < 4; ++ii)                                          \
        NAA[ii] = *(const half8*)&As[(((BB) + 1) & 3) * 8192 + aoff + ii * 512]; \
    }                                                                         \
    __builtin_amdgcn_sched_barrier(0);                                        \
    __builtin_amdgcn_s_setprio(1);                                            \
    _Pragma("unroll")                                                         \
    for (int ii = 0; ii < 4; ++ii)                                            \
      _Pragma("unroll")                                                       \
      for (int jj = 0; jj < 4; ++jj)                                          \
        acc[ii][jj] = __builtin_amdgcn_mfma_f32_16x16x32_f16(                 \
            CAA[ii], CBF[jj], acc[ii][jj], 0, 0, 0);                          \
    __builtin_amdgcn_s_setprio(0);                                            \
    __builtin_amdgcn_sched_barrier(0);                                        \
    __builtin_amdgcn_s_setprio(1);                                            \
    _Pragma("unroll")                                                         \
    for (int ii = 0; ii < 4; ++ii)                                            \
      _Pragma("unroll")                                                       \
      for (int jj = 0; jj < 4; ++jj)                                          \
        acc[ii + 4][jj] = __builtin_amdgcn_mfma_f32_16x16x32_f16(             \
            CAB[ii], CBF[jj], acc[ii + 4][jj], 0, 0, 0);                      \
    __builtin_amdgcn_s_setprio(0);                                            \
    asm volatile("s_waitcnt lgkmcnt(0)" ::: "memory");                        \
  }

  // Prologue: stage tiles 0..2; confirm tile 0; prime cur fragments.
  STAGE(0);
  STAGE(1);
  STAGE(2);
  asm volatile("s_waitcnt vmcnt(8)" ::: "memory");   // tile 0 landed
  __builtin_amdgcn_s_barrier();
  __builtin_amdgcn_sched_barrier(0);
  half8 aA0[4], bF0[4], aB0[4], aA1[4], bF1[4], aB1[4];
#pragma unroll
  for (int jj = 0; jj < 4; ++jj) bF0[jj] = *(const half8*)&Bs[boff + jj * 512];
#pragma unroll
  for (int ii = 0; ii < 4; ++ii) aA0[ii] = *(const half8*)&As[aoff + ii * 512];

  const int T = K >> 5;               // 84 for K=2688 (divisible by 4)
  for (int t4 = 0; t4 < T - 4; t4 += 4) {
    KITER(0, aA0, bF0, aB0, aA1, bF1, "4", 1, 1);
    KITER(1, aA1, bF1, aB1, aA0, bF0, "4", 1, 1);
    KITER(2, aA0, bF0, aB0, aA1, bF1, "4", 1, 1);
    KITER(3, aA1, bF1, aB1, aA0, bF0, "4", 1, 1);
  }
  KITER(0, aA0, bF0, aB0, aA1, bF1, "4", 1, 1);   // t = T-4, stages T-1
  KITER(1, aA1, bF1, aB1, aA0, bF0, "4", 0, 1);   // t = T-3
  KITER(2, aA0, bF0, aB0, aA1, bF1, "0", 0, 1);   // t = T-2
  KITER(3, aA1, bF1, aB1, aA0, bF0, "0", 0, 0);   // t = T-1
#undef KITER
#undef STAGE

  // C/D layout: col = lane&15, row = quad*4 + reg
#pragma unroll
  for (int ii = 0; ii < 8; ++ii) {
    size_t r = row0 + wm * 128 + ii * 16 + quad * 4;
#pragma unroll
    for (int jj = 0; jj < 4; ++jj) {
      size_t cc = col0 + wn * 64 + jj * 16 + m16;
#pragma unroll
      for (int rr = 0; rr < 4; ++rr) {
        float v = acc[ii][jj][rr];
        if (SILU) v = v / (1.f + __expf(-v));
        C[(r + rr) * ldc + cc] = (_Float16)v;
      }
    }
  }
}

// ---------------------------------------------------------------------------
// epi0: o0 = (f0 .* g0) @ w0.  32 rows/block, BK=64, K=2688, N=64. grid 256.
// (round-2 verbatim)
// ---------------------------------------------------------------------------
__global__ __launch_bounds__(256) void epi0_kernel(
    const _Float16* __restrict__ f0p, const _Float16* __restrict__ G,
    const _Float16* __restrict__ w0T, float* __restrict__ out) {
  __shared__ alignas(16) _Float16 As[32 * 64];
  const int t = threadIdx.x;
  const size_t n0 = (size_t)blockIdx.x * 32;
  const int lane = t & 63, wave = t >> 6;
  const int m16 = lane & 15, quad = lane >> 4;
  const int rt = (wave & 1) * 16;        // row tile base
  const int ctb = (wave >> 1) * 32;      // col pair base
  const int br = t >> 3, p = t & 7;      // build: row, physical chunk
  const int l8 = (p ^ (br & 7)) * 8;     // logical k offset

  floatx4 acc[2] = {};
  for (int k0 = 0; k0 < KP; k0 += 64) {
    if (k0) __syncthreads();
    {
      half8 f = *(const half8*)&f0p[(n0 + br) * KP + k0 + l8];
      half8 g = *(const half8*)&G[(n0 + br) * NP2 + k0 + l8];
      half8 a;
#pragma unroll
      for (int j = 0; j < 8; ++j) a[j] = (_Float16)((float)f[j] * (float)g[j]);
      *(half8*)&As[br * 64 + p * 8] = a;
    }
    __syncthreads();
#pragma unroll
    for (int kk = 0; kk < 2; ++kk) {
      int q = kk * 4 + quad;
      half8 af = *(const half8*)&As[(rt + m16) * 64 + (q ^ (m16 & 7)) * 8];
#pragma unroll
      for (int c = 0; c < 2; ++c) {
        half8 bf = *(const half8*)&w0T[(size_t)(ctb + c * 16 + m16) * KP + k0 + kk * 32 + quad * 8];
        acc[c] = __builtin_amdgcn_mfma_f32_16x16x32_f16(af, bf, acc[c], 0, 0, 0);
      }
    }
  }
#pragma unroll
  for (int c = 0; c < 2; ++c)
#pragma unroll
    for (int rr = 0; rr < 4; ++rr)
      out[(n0 + rt + quad * 4 + rr) * 288 + ctb + c * 16 + m16] = acc[c][rr];
}

// ---------------------------------------------------------------------------
// epi1: o1[n][o][i] = sum_c f1[n][c][i]*g1[n][c]*w1o[c][o].  (round-2 verbatim)
// ---------------------------------------------------------------------------
__global__ __launch_bounds__(256) void epi1_kernel(
    const float* __restrict__ xs_g, const float* __restrict__ xv_g,
    const _Float16* __restrict__ G, const _Float16* __restrict__ w1oT,
    float* __restrict__ out) {
  __shared__ float xs[32][64];
  __shared__ float xv[32][96];
  __shared__ alignas(16) _Float16 As[3][32 * 64];
  const int t = threadIdx.x;
  const size_t n0 = (size_t)blockIdx.x * 32;
  for (int idx = t; idx < 32 * 64; idx += 256)
    xs[idx >> 6][idx & 63] = xs_g[(n0 + (idx >> 6)) * 64 + (idx & 63)];
  for (int idx = t; idx < 32 * 96; idx += 256)
    xv[idx / 96][idx % 96] = xv_g[(n0 + idx / 96) * 96 + idx % 96];
  const int lane = t & 63, wave = t >> 6;
  const int m16 = lane & 15, quad = lane >> 4;
  const int rt = (wave & 1) * 16;   // row tile
  const int ct = (wave >> 1) * 16;  // col tile
  const int br = t >> 3, p = t & 7;
  const int l8 = (p ^ (br & 7)) * 8;

  floatx4 acc[3] = {};
  __syncthreads();
  for (int k0 = 0; k0 < M1P; k0 += 64) {
    if (k0) __syncthreads();
    {
      half8 g8 = *(const half8*)&G[(n0 + br) * NP2 + M0C + k0 + l8];
      int kbase = k0 + l8;
      half8 a0, a1, a2;
      if (kbase < 32) {
#pragma unroll
        for (int j = 0; j < 8; ++j) {
          float g = (float)g8[j];
          int v = kbase + j;
          a0[j] = (_Float16)(xv[br][v * 3 + 0] * g);
          a1[j] = (_Float16)(xv[br][v * 3 + 1] * g);
          a2[j] = (_Float16)(xv[br][v * 3 + 2] * g);
        }
      } else {
        int s = (kbase - 32) >> 5;
        if (s > 63) s = 63;                  // pad region: B is zero anyway
        int v0 = (kbase - 32) & 31;
        float xsr = xs[br][s];
#pragma unroll
        for (int j = 0; j < 8; ++j) {
          float g = (float)g8[j] * xsr;
          int v = v0 + j;
          a0[j] = (_Float16)(xv[br][v * 3 + 0] * g);
          a1[j] = (_Float16)(xv[br][v * 3 + 1] * g);
          a2[j] = (_Float16)(xv[br][v * 3 + 2] * g);
        }
      }
      *(half8*)&As[0][br * 64 + p * 8] = a0;
      *(half8*)&As[1][br * 64 + p * 8] = a1;
      *(half8*)&As[2][br * 64 + p * 8] = a2;
    }
    __syncthreads();
#pragma unroll
    for (int kk = 0; kk < 2; ++kk) {
      int q = kk * 4 + quad;
      half8 bf = *(const half8*)&w1oT[(size_t)(ct + m16) * M1P + k0 + kk * 32 + quad * 8];
#pragma unroll
      for (int i = 0; i < 3; ++i) {
        half8 af = *(const half8*)&As[i][(rt + m16) * 64 + (q ^ (m16 & 7)) * 8];
        acc[i] = __builtin_amdgcn_mfma_f32_16x16x32_f16(af, bf, acc[i], 0, 0, 0);
      }
    }
  }
#pragma unroll
  for (int i = 0; i < 3; ++i)
#pragma unroll
    for (int rr = 0; rr < 4; ++rr)
      out[(n0 + rt + quad * 4 + rr) * 288 + 64 + (ct + m16) * 3 + i] = acc[i][rr];
}

// ---------------------------------------------------------------------------
// epi1e2: blockIdx.y==0 -> o1e (K=496->512), ==1 -> o2 (K=528->544).
// (round-2 verbatim)
// ---------------------------------------------------------------------------
__global__ __launch_bounds__(256) void epi1e2_kernel(
    const float* __restrict__ xv_g, const _Float16* __restrict__ G,
    const _Float16* __restrict__ w1eT, const _Float16* __restrict__ w2eT,
    float* __restrict__ out) {
  __shared__ float xv[64][96];
  __shared__ alignas(16) _Float16 As[5][64 * 32];
  __shared__ uint8_t pa[544], pb[544];
  const int t = threadIdx.x;
  const size_t n0 = (size_t)blockIdx.x * 64;
  const int phase = blockIdx.y;
  for (int idx = t; idx < 64 * 96; idx += 256)
    xv[idx / 96][idx % 96] = xv_g[(n0 + idx / 96) * 96 + idx % 96];
  for (int p = t; p < 544; p += 256) {
    int a = 0, b = 0;
    if (phase == 0) {
      if (p < A1C) { triu_ab(p, 31, a, b); b += 1; }
    } else {
      if (p < P1C) triu_ab(p, 32, a, b);
    }
    pa[p] = (uint8_t)a; pb[p] = (uint8_t)b;
  }
  const int lane = t & 63, wave = t >> 6;
  const int m16 = lane & 15, quad = lane >> 4;
  const int sw8 = (quad ^ ((m16 >> 1) & 3)) * 8;
  const int br = t >> 2;
  const int bc8 = ((t & 3) ^ ((br >> 1) & 3)) * 8;  // swizzled source chunk
  const int lc8 = (t & 3) * 8;                      // LDS column
  const float s2 = 0.70710678118654752f, s6 = 0.40824829046386302f;
  __syncthreads();

  if (phase == 0) {  // ---- o1e: cross pairs ----
    floatx4 acc[3] = {};
    for (int k0 = 0; k0 < 512; k0 += 32) {
      if (k0) __syncthreads();
      {
        half8 g8 = *(const half8*)&G[(n0 + br) * NP2 + (M0C + M1C) + k0 + bc8];
        half8 a0, a1, a2;
#pragma unroll
        for (int j = 0; j < 8; ++j) {
          int p = k0 + bc8 + j;
          if (p < A1C) {
            int a = pa[p], b = pb[p];
            float ax = xv[br][a * 3], ay = xv[br][a * 3 + 1], az = xv[br][a * 3 + 2];
            float bx = xv[br][b * 3], by = xv[br][b * 3 + 1], bz = xv[br][b * 3 + 2];
            float g = (float)g8[j] * s2;
            a0[j] = (_Float16)((ay * bz - az * by) * g);
            a1[j] = (_Float16)((az * bx - ax * bz) * g);
            a2[j] = (_Float16)((ax * by - ay * bx) * g);
          } else {
            a0[j] = (_Float16)0.f; a1[j] = (_Float16)0.f; a2[j] = (_Float16)0.f;
          }
        }
        *(half8*)&As[0][br * 32 + lc8] = a0;
        *(half8*)&As[1][br * 32 + lc8] = a1;
        *(half8*)&As[2][br * 32 + lc8] = a2;
      }
      __syncthreads();
      half8 bf = *(const half8*)&w1eT[(size_t)m16 * 512 + k0 + quad * 8];
#pragma unroll
      for (int i = 0; i < 3; ++i) {
        half8 af = *(const half8*)&As[i][(wave * 16 + m16) * 32 + sw8];
        acc[i] = __builtin_amdgcn_mfma_f32_16x16x32_f16(af, bf, acc[i], 0, 0, 0);
      }
    }
#pragma unroll
    for (int i = 0; i < 3; ++i)
#pragma unroll
      for (int rr = 0; rr < 4; ++rr)
        out[(n0 + wave * 16 + quad * 4 + rr) * 288 + 160 + m16 * 3 + i] = acc[i][rr];
  } else {  // ---- o2: symmetric pairs ----
    floatx4 acc[5] = {};
    for (int k0 = 0; k0 < 544; k0 += 32) {
      if (k0) __syncthreads();
      {
        half8 g8 = *(const half8*)&G[(n0 + br) * NP2 + (M0C + M1C + A1C) + k0 + bc8];
        half8 m0v, m1v, m2v, m3v, m4v;
#pragma unroll
        for (int j = 0; j < 8; ++j) {
          int p = k0 + bc8 + j;
          if (p < P1C) {
            int a = pa[p], b = pb[p];
            float ax = xv[br][a * 3], ay = xv[br][a * 3 + 1], az = xv[br][a * 3 + 2];
            float bx = xv[br][b * 3], by = xv[br][b * 3 + 1], bz = xv[br][b * 3 + 2];
            float c1 = (a == b) ? s2 : 1.f;
            float gw = (float)g8[j] * c1;
            m0v[j] = (_Float16)(s2 * (ax * by + ay * bx) * gw);
            m1v[j] = (_Float16)(s2 * (ay * bz + az * by) * gw);
            m2v[j] = (_Float16)(s2 * (ax * bz + az * bx) * gw);
            m3v[j] = (_Float16)(s2 * (ax * bx - ay * by) * gw);
            m4v[j] = (_Float16)(s6 * (2.f * az * bz - ax * bx - ay * by) * gw);
          } else {
            m0v[j] = (_Float16)0.f; m1v[j] = (_Float16)0.f; m2v[j] = (_Float16)0.f;
            m3v[j] = (_Float16)0.f; m4v[j] = (_Float16)0.f;
          }
        }
        *(half8*)&As[0][br * 32 + lc8] = m0v;
        *(half8*)&As[1][br * 32 + lc8] = m1v;
        *(half8*)&As[2][br * 32 + lc8] = m2v;
        *(half8*)&As[3][br * 32 + lc8] = m3v;
        *(half8*)&As[4][br * 32 + lc8] = m4v;
      }
      __syncthreads();
      half8 bf = *(const half8*)&w2eT[(size_t)m16 * 544 + k0 + quad * 8];
#pragma unroll
      for (int m = 0; m < 5; ++m) {
        half8 af = *(const half8*)&As[m][(wave * 16 + m16) * 32 + sw8];
        acc[m] = __builtin_amdgcn_mfma_f32_16x16x32_f16(af, bf, acc[m], 0, 0, 0);
      }
    }
#pragma unroll
    for (int m = 0; m < 5; ++m)
#pragma unroll
      for (int rr = 0; rr < 4; ++rr)
        out[(n0 + wave * 16 + quad * 4 + rr) * 288 + 208 + m16 * 5 + m] = acc[m][rr];
  }
}

// ---------------------------------------------------------------------------
extern "C" void kernel_launch(void* const* d_in, const int* in_sizes, int n_in,
                              void* d_out, int out_size, void* d_ws, size_t ws_size,
                              hipStream_t stream) {
  const float* xs  = (const float*)d_in[0];
  const float* xv  = (const float*)d_in[1];
  const float* w1  = (const float*)d_in[2];
  const float* w2  = (const float*)d_in[3];
  const float* w0  = (const float*)d_in[4];
  const float* w1o = (const float*)d_in[5];
  const float* w1e = (const float*)d_in[6];
  const float* w2e = (const float*)d_in[7];
  float* out = (float*)d_out;

  char* ws = (char*)d_ws;
  size_t off = 0;
  _Float16* w1T = (_Float16*)(ws + off); off += (size_t)NPAD1 * KP * 2;    // 15.14 MB
  _Float16* w2T = (_Float16*)(ws + off); off += (size_t)NP2 * KP * 2;      // 31.65 MB
  _Float16* f0p = (_Float16*)(ws + off); off += (size_t)N_ROWS * KP * 2;   // 44.04 MB
  _Float16* H   = (_Float16*)(ws + off); off += (size_t)N_ROWS * NPAD1 * 2;// 46.14 MB
  _Float16* G   = (_Float16*)(ws + off);                                   // 96.47 MB
  // total ~233.4 MB

  // Small epilogue weights live inside w1T's region (dead after GEMM1).
  _Float16* w0T  = w1T;                                     // 64 x 2688 = 344064 B
  _Float16* w1oT = (_Float16*)((char*)w1T + 344064);        // 32 x 2112 = 135168 B
  _Float16* w1eT = (_Float16*)((char*)w1T + 479232);        // 32 x 512  =  32768 B
  _Float16* w2eT = (_Float16*)((char*)w1T + 512000);        // 32 x 544  =  34816 B

  transpose_cvt_kernel<<<dim3(KP / 32, NPAD1 / 32), 256, 0, stream>>>(w1, w1T, M0C, M0C, KP);
  transpose_cvt_kernel<<<dim3(KP / 32, NP2 / 32), 256, 0, stream>>>(w2, w2T, M0C, NIR, KP);
  build_f0_kernel<<<N_ROWS, 256, 0, stream>>>(xs, xv, f0p);
  gemm256_kernel<true><<<dim3(NPAD1 / 256, N_ROWS / 256), 512, 0, stream>>>(
      f0p, w1T, H, KP, KP, KP, NPAD1);
  // w1T now dead -> overwrite with epilogue weights
  transpose_cvt_kernel<<<dim3(KP / 32, 2), 256, 0, stream>>>(w0, w0T, M0C, 64, KP);
  transpose_cvt_kernel<<<dim3(M1P / 32, 1), 256, 0, stream>>>(w1o, w1oT, M1C, 32, M1P);
  transpose_cvt_kernel<<<dim3(16, 1), 256, 0, stream>>>(w1e, w1eT, A1C, 16, 512);
  transpose_cvt_kernel<<<dim3(17, 1), 256, 0, stream>>>(w2e, w2eT, P1C, 16, 544);
  gemm256_kernel<false><<<dim3(NP2 / 256, N_ROWS / 256), 512, 0, stream>>>(
      H, w2T, G, KP, NPAD1, KP, NP2);
  epi0_kernel<<<256, 256, 0, stream>>>(f0p, G, w0T, out);
  epi1_kernel<<<256, 256, 0, stream>>>(xs, xv, G, w1oT, out);
  epi1e2_kernel<<<dim3(128, 2), 256, 0, stream>>>(xv, G, w1eT, w2eT, out);
}

// Round 8
// 725.689 us; speedup vs baseline: 1.1289x; 1.0349x over previous
//
#include <hip/hip_runtime.h>
#include <hip/hip_bf16.h>
#include <stdint.h>

// Problem constants
#define N_ROWS 8192
#define M0C 2672    // C0 + P0 + P1 = 64 + 2080 + 528
#define M1C 2080    // C1 + C0*C1
#define A1C 496
#define P1C 528
#define KP  2688    // M0 padded to multiple of 128 (and 32 for BK)
#define NP2 5888    // NUM_IRREPS (5776) padded to multiple of 256
#define NIR 5776
#define M1P 2112    // M1C padded to multiple of 64
#define NPAD1 2816  // GEMM1 N (=M0) padded to multiple of 256 (11*256)

typedef __attribute__((ext_vector_type(8))) _Float16 half8;
typedef __attribute__((ext_vector_type(4))) float floatx4;

__device__ __forceinline__ void async_copy16(const _Float16* g, _Float16* l) {
  __builtin_amdgcn_global_load_lds(
      (__attribute__((address_space(1))) void*)(g),
      (__attribute__((address_space(3))) void*)(l), 16, 0, 0);
}

// ---------------------------------------------------------------------------
// Transpose + fp32->fp16 convert with zero padding.  (round-2 verbatim)
// ---------------------------------------------------------------------------
__global__ __launch_bounds__(256) void transpose_cvt_kernel(
    const float* __restrict__ src, _Float16* __restrict__ dst,
    int srcR, int srcC, int dstC) {
  __shared__ float tile[32][33];
  const int t = threadIdx.x, tx = t & 31, ty = t >> 5;
  const int bx = blockIdx.x, by = blockIdx.y;
#pragma unroll
  for (int i = 0; i < 4; ++i) {
    int sr = bx * 32 + ty + i * 8;   // src row (k dim)
    int sc = by * 32 + tx;           // src col
    tile[ty + i * 8][tx] = (sr < srcR && sc < srcC) ? src[(size_t)sr * srcC + sc] : 0.f;
  }
  __syncthreads();
#pragma unroll
  for (int i = 0; i < 4; ++i) {
    int dr = by * 32 + ty + i * 8;
    int dc = bx * 32 + tx;
    dst[(size_t)dr * dstC + dc] = (_Float16)tile[tx][ty + i * 8];
  }
}

// ---------------------------------------------------------------------------
// triu_indices(C) pair decode: p -> (a, b), b >= a.
// ---------------------------------------------------------------------------
__device__ __forceinline__ void triu_ab(int p, int C, int& a, int& b) {
  float fC = (float)C + 0.5f;
  int ai = (int)(fC - sqrtf(fC * fC - 2.0f * (float)p));
  if (ai < 0) ai = 0;
  while (ai > 0 && ai * C - ai * (ai - 1) / 2 > p) --ai;
  while ((ai + 1) * C - (ai + 1) * ai / 2 <= p) ++ai;
  a = ai;
  b = p - (ai * C - ai * (ai - 1) / 2) + ai;
}

// ---------------------------------------------------------------------------
// f0 = [x_s (64) | ss (2080) | vv0 (528) | zero pad (16)]  as fp16 [N][KP]
// (round-2 verbatim)
// ---------------------------------------------------------------------------
__global__ __launch_bounds__(256) void build_f0_kernel(
    const float* __restrict__ xs_g, const float* __restrict__ xv_g,
    _Float16* __restrict__ f0p) {
  __shared__ float xs[64];
  __shared__ float xv[96];
  const int t = threadIdx.x;
  const size_t n = blockIdx.x;
  if (t < 64) xs[t] = xs_g[n * 64 + t];
  else if (t < 160) xv[t - 64] = xv_g[n * 96 + (t - 64)];
  __syncthreads();
  for (int c = t; c < KP; c += 256) {
    float v;
    if (c < 64) {
      v = xs[c];
    } else if (c < 2144) {                       // ss: pair products of x_s
      int a, b;
      triu_ab(c - 64, 64, a, b);
      v = xs[a] * xs[b] * ((a == b) ? 0.70710678118654752f : 1.f);
    } else if (c < M0C) {                        // vv0: pair dots of x_v
      int a, b;
      triu_ab(c - 2144, 32, a, b);
      float d = xv[a * 3] * xv[b * 3] + xv[a * 3 + 1] * xv[b * 3 + 1] +
                xv[a * 3 + 2] * xv[b * 3 + 2];
      v = d * ((a == b) ? 0.70710678118654752f : 1.f) * 0.57735026918962576f;
    } else {
      v = 0.f;                                   // pad
    }
    f0p[n * KP + c] = (_Float16)v;
  }
}

// ---------------------------------------------------------------------------
// fp16 MFMA GEMM, 256x256 tile, BK=32, 8 waves (wave tile 128x64).
// Round-7: round-1's overlapped stage position with a PROVABLY race-free
// ring distance.  Per iter t: {STAGE slot (t+2)&3; vmcnt(4); barrier;
// ds_reads (aHi of t, aLo/bF of t+1); MFMAs; lgkmcnt(0)}.
// Race-freedom: slot (t+2)&3 == (t-2) mod 4; its last readers (iter t-2)
// lgkm-drain before reaching bar(t-1), and the overwriting wave issues
// STAGE(t+2) only after passing bar(t-1) -> one barrier of separation.
// (Round-1's bug was +3 == t-1: ZERO barriers of separation.)
// vmcnt(4) pre-barrier: outstanding = stage(t+1)+stage(t+2) = 8; waiting
// to 4 confirms tile t+1 for the post-barrier next-tile reads.
// Prologue stages slots 0,1; tail vmcnt 4,4,0,0.
// B stored transposed [N][K]. Requires K % 128 == 0.
// ---------------------------------------------------------------------------
template <bool SILU>
__global__ __launch_bounds__(512, 2) void gemm256_kernel(
    const _Float16* __restrict__ A, const _Float16* __restrict__ B,
    _Float16* __restrict__ C, int K, int lda, int ldb, int ldc) {
  __shared__ alignas(16) _Float16 As[4 * 8192];
  __shared__ alignas(16) _Float16 Bs[4 * 8192];
  const int tid = threadIdx.x;

  // XCD-aware bijective remap.
  const int ncol = gridDim.x;
  const int id = blockIdx.y * ncol + blockIdx.x;
  const int xcd = id & 7;
  const int j = id >> 3;
  const int hb = j / (2 * ncol);
  const int w = j - hb * 2 * ncol;
  const int by = xcd * 4 + hb * 2 + (w & 1);
  const int bx = w >> 1;
  const size_t row0 = (size_t)by * 256;
  const size_t col0 = (size_t)bx * 256;

  const _Float16 *pA0, *pA1, *pB0, *pB1;
  _Float16 *lA0, *lA1, *lB0, *lB1;
  {
    int c0 = tid, c1 = tid + 512;
    int r0 = c0 >> 2, ch0 = c0 & 3;
    int r1 = c1 >> 2, ch1 = c1 & 3;
    int s0 = ch0 ^ ((r0 >> 1) & 3);
    int s1 = ch1 ^ ((r1 >> 1) & 3);
    pA0 = A + (row0 + r0) * lda + s0 * 8;
    pA1 = A + (row0 + r1) * lda + s1 * 8;
    pB0 = B + (col0 + r0) * ldb + s0 * 8;
    pB1 = B + (col0 + r1) * ldb + s1 * 8;
    lA0 = &As[c0 * 8]; lA1 = &As[c1 * 8];
    lB0 = &Bs[c0 * 8]; lB1 = &Bs[c1 * 8];
  }

  const int lane = tid & 63;
  const int wv = tid >> 6;
  const int wm = wv & 1;
  const int wn = wv >> 1;
  const int m16 = lane & 15;
  const int quad = lane >> 4;
  const int sw8 = (quad ^ ((m16 >> 1) & 3)) * 8;
  const int aoff = (wm * 128 + m16) * 32 + sw8;
  const int boff = (wn * 64 + m16) * 32 + sw8;

  floatx4 acc[8][4] = {};

#define STAGE(BB)                                             \
  {                                                           \
    async_copy16(pA0, lA0 + (BB) * 8192);                     \
    async_copy16(pA1, lA1 + (BB) * 8192);                     \
    async_copy16(pB0, lB0 + (BB) * 8192);                     \
    async_copy16(pB1, lB1 + (BB) * 8192);                     \
    pA0 += 32; pA1 += 32; pB0 += 32; pB1 += 32;               \
  }

#define KITER(BB, CAA, CBF, CAB, NAA, NBF, VMLIT, DO_STAGE, DO_READN)         \
  {                                                                           \
    if (DO_STAGE) STAGE(((BB) + 2) & 3);                                      \
    asm volatile("s_waitcnt vmcnt(" VMLIT ")" ::: "memory");                  \
    __builtin_amdgcn_s_barrier();                                             \
    __builtin_amdgcn_sched_barrier(0);                                        \
    _Pragma("unroll")                                                         \
    for (int ii = 0; ii < 4; ++ii)                                            \
      CAB[ii] = *(const half8*)&As[(BB) * 8192 + aoff + (ii + 4) * 512];      \
    if (DO_READN) {                                                           \
      _Pragma("unroll")                                                       \
      for (int jj = 0; jj < 4; ++jj)                                          \
        NBF[jj] = *(const half8*)&Bs[(((BB) + 1) & 3) * 8192 + boff + jj * 512]; \
      _Pragma("unroll")                                                       \
      for (int ii = 0; ii < 4; ++ii)                                          \
        NAA[ii] = *(const half8*)&As[(((BB) + 1) & 3) * 8192 + aoff + ii * 512]; \
    }                                                                         \
    __builtin_amdgcn_sched_barrier(0);                                        \
    __builtin_amdgcn_s_setprio(1);                                            \
    _Pragma("unroll")                                                         \
    for (int ii = 0; ii < 4; ++ii)                                            \
      _Pragma("unroll")                                                       \
      for (int jj = 0; jj < 4; ++jj)                                          \
        acc[ii][jj] = __builtin_amdgcn_mfma_f32_16x16x32_f16(                 \
            CAA[ii], CBF[jj], acc[ii][jj], 0, 0, 0);                          \
    __builtin_amdgcn_s_setprio(0);                                            \
    __builtin_amdgcn_sched_barrier(0);                                        \
    __builtin_amdgcn_s_setprio(1);                                            \
    _Pragma("unroll")                                                         \
    for (int ii = 0; ii < 4; ++ii)                                            \
      _Pragma("unroll")                                                       \
      for (int jj = 0; jj < 4; ++jj)                                          \
        acc[ii + 4][jj] = __builtin_amdgcn_mfma_f32_16x16x32_f16(             \
            CAB[ii], CBF[jj], acc[ii + 4][jj], 0, 0, 0);                      \
    __builtin_amdgcn_s_setprio(0);                                            \
    asm volatile("s_waitcnt lgkmcnt(0)" ::: "memory");                        \
  }

  // Prologue: stage tiles 0,1; confirm tile 0; prime cur fragments.
  STAGE(0);
  STAGE(1);
  asm volatile("s_waitcnt vmcnt(4)" ::: "memory");   // tile 0 landed
  __builtin_amdgcn_s_barrier();
  __builtin_amdgcn_sched_barrier(0);
  half8 aA0[4], bF0[4], aB0[4], aA1[4], bF1[4], aB1[4];
#pragma unroll
  for (int jj = 0; jj < 4; ++jj) bF0[jj] = *(const half8*)&Bs[boff + jj * 512];
#pragma unroll
  for (int ii = 0; ii < 4; ++ii) aA0[ii] = *(const half8*)&As[aoff + ii * 512];

  const int T = K >> 5;               // 84 for K=2688 (divisible by 4)
  for (int t4 = 0; t4 < T - 4; t4 += 4) {
    KITER(0, aA0, bF0, aB0, aA1, bF1, "4", 1, 1);
    KITER(1, aA1, bF1, aB1, aA0, bF0, "4", 1, 1);
    KITER(2, aA0, bF0, aB0, aA1, bF1, "4", 1, 1);
    KITER(3, aA1, bF1, aB1, aA0, bF0, "4", 1, 1);
  }
  KITER(0, aA0, bF0, aB0, aA1, bF1, "4", 1, 1);   // t = T-4, stages T-2
  KITER(1, aA1, bF1, aB1, aA0, bF0, "4", 1, 1);   // t = T-3, stages T-1
  KITER(2, aA0, bF0, aB0, aA1, bF1, "0", 0, 1);   // t = T-2
  KITER(3, aA1, bF1, aB1, aA0, bF0, "0", 0, 0);   // t = T-1
#undef KITER
#undef STAGE

  // C/D layout: col = lane&15, row = quad*4 + reg
#pragma unroll
  for (int ii = 0; ii < 8; ++ii) {
    size_t r = row0 + wm * 128 + ii * 16 + quad * 4;
#pragma unroll
    for (int jj = 0; jj < 4; ++jj) {
      size_t cc = col0 + wn * 64 + jj * 16 + m16;
#pragma unroll
      for (int rr = 0; rr < 4; ++rr) {
        float v = acc[ii][jj][rr];
        if (SILU) v = v / (1.f + __expf(-v));
        C[(r + rr) * ldc + cc] = (_Float16)v;
      }
    }
  }
}

// ---------------------------------------------------------------------------
// epi0: o0 = (f0 .* g0) @ w0.  32 rows/block, BK=64, K=2688, N=64. grid 256.
// (round-2 verbatim)
// ---------------------------------------------------------------------------
__global__ __launch_bounds__(256) void epi0_kernel(
    const _Float16* __restrict__ f0p, const _Float16* __restrict__ G,
    const _Float16* __restrict__ w0T, float* __restrict__ out) {
  __shared__ alignas(16) _Float16 As[32 * 64];
  const int t = threadIdx.x;
  const size_t n0 = (size_t)blockIdx.x * 32;
  const int lane = t & 63, wave = t >> 6;
  const int m16 = lane & 15, quad = lane >> 4;
  const int rt = (wave & 1) * 16;        // row tile base
  const int ctb = (wave >> 1) * 32;      // col pair base
  const int br = t >> 3, p = t & 7;      // build: row, physical chunk
  const int l8 = (p ^ (br & 7)) * 8;     // logical k offset

  floatx4 acc[2] = {};
  for (int k0 = 0; k0 < KP; k0 += 64) {
    if (k0) __syncthreads();
    {
      half8 f = *(const half8*)&f0p[(n0 + br) * KP + k0 + l8];
      half8 g = *(const half8*)&G[(n0 + br) * NP2 + k0 + l8];
      half8 a;
#pragma unroll
      for (int j = 0; j < 8; ++j) a[j] = (_Float16)((float)f[j] * (float)g[j]);
      *(half8*)&As[br * 64 + p * 8] = a;
    }
    __syncthreads();
#pragma unroll
    for (int kk = 0; kk < 2; ++kk) {
      int q = kk * 4 + quad;
      half8 af = *(const half8*)&As[(rt + m16) * 64 + (q ^ (m16 & 7)) * 8];
#pragma unroll
      for (int c = 0; c < 2; ++c) {
        half8 bf = *(const half8*)&w0T[(size_t)(ctb + c * 16 + m16) * KP + k0 + kk * 32 + quad * 8];
        acc[c] = __builtin_amdgcn_mfma_f32_16x16x32_f16(af, bf, acc[c], 0, 0, 0);
      }
    }
  }
#pragma unroll
  for (int c = 0; c < 2; ++c)
#pragma unroll
    for (int rr = 0; rr < 4; ++rr)
      out[(n0 + rt + quad * 4 + rr) * 288 + ctb + c * 16 + m16] = acc[c][rr];
}

// ---------------------------------------------------------------------------
// epi1: o1[n][o][i] = sum_c f1[n][c][i]*g1[n][c]*w1o[c][o].  (round-2 verbatim)
// ---------------------------------------------------------------------------
__global__ __launch_bounds__(256) void epi1_kernel(
    const float* __restrict__ xs_g, const float* __restrict__ xv_g,
    const _Float16* __restrict__ G, const _Float16* __restrict__ w1oT,
    float* __restrict__ out) {
  __shared__ float xs[32][64];
  __shared__ float xv[32][96];
  __shared__ alignas(16) _Float16 As[3][32 * 64];
  const int t = threadIdx.x;
  const size_t n0 = (size_t)blockIdx.x * 32;
  for (int idx = t; idx < 32 * 64; idx += 256)
    xs[idx >> 6][idx & 63] = xs_g[(n0 + (idx >> 6)) * 64 + (idx & 63)];
  for (int idx = t; idx < 32 * 96; idx += 256)
    xv[idx / 96][idx % 96] = xv_g[(n0 + idx / 96) * 96 + idx % 96];
  const int lane = t & 63, wave = t >> 6;
  const int m16 = lane & 15, quad = lane >> 4;
  const int rt = (wave & 1) * 16;   // row tile
  const int ct = (wave >> 1) * 16;  // col tile
  const int br = t >> 3, p = t & 7;
  const int l8 = (p ^ (br & 7)) * 8;

  floatx4 acc[3] = {};
  __syncthreads();
  for (int k0 = 0; k0 < M1P; k0 += 64) {
    if (k0) __syncthreads();
    {
      half8 g8 = *(const half8*)&G[(n0 + br) * NP2 + M0C + k0 + l8];
      int kbase = k0 + l8;
      half8 a0, a1, a2;
      if (kbase < 32) {
#pragma unroll
        for (int j = 0; j < 8; ++j) {
          float g = (float)g8[j];
          int v = kbase + j;
          a0[j] = (_Float16)(xv[br][v * 3 + 0] * g);
          a1[j] = (_Float16)(xv[br][v * 3 + 1] * g);
          a2[j] = (_Float16)(xv[br][v * 3 + 2] * g);
        }
      } else {
        int s = (kbase - 32) >> 5;
        if (s > 63) s = 63;                  // pad region: B is zero anyway
        int v0 = (kbase - 32) & 31;
        float xsr = xs[br][s];
#pragma unroll
        for (int j = 0; j < 8; ++j) {
          float g = (float)g8[j] * xsr;
          int v = v0 + j;
          a0[j] = (_Float16)(xv[br][v * 3 + 0] * g);
          a1[j] = (_Float16)(xv[br][v * 3 + 1] * g);
          a2[j] = (_Float16)(xv[br][v * 3 + 2] * g);
        }
      }
      *(half8*)&As[0][br * 64 + p * 8] = a0;
      *(half8*)&As[1][br * 64 + p * 8] = a1;
      *(half8*)&As[2][br * 64 + p * 8] = a2;
    }
    __syncthreads();
#pragma unroll
    for (int kk = 0; kk < 2; ++kk) {
      int q = kk * 4 + quad;
      half8 bf = *(const half8*)&w1oT[(size_t)(ct + m16) * M1P + k0 + kk * 32 + quad * 8];
#pragma unroll
      for (int i = 0; i < 3; ++i) {
        half8 af = *(const half8*)&As[i][(rt + m16) * 64 + (q ^ (m16 & 7)) * 8];
        acc[i] = __builtin_amdgcn_mfma_f32_16x16x32_f16(af, bf, acc[i], 0, 0, 0);
      }
    }
  }
#pragma unroll
  for (int i = 0; i < 3; ++i)
#pragma unroll
    for (int rr = 0; rr < 4; ++rr)
      out[(n0 + rt + quad * 4 + rr) * 288 + 64 + (ct + m16) * 3 + i] = acc[i][rr];
}

// ---------------------------------------------------------------------------
// epi1e2: blockIdx.y==0 -> o1e (K=496->512), ==1 -> o2 (K=528->544).
// (round-2 verbatim)
// ---------------------------------------------------------------------------
__global__ __launch_bounds__(256) void epi1e2_kernel(
    const float* __restrict__ xv_g, const _Float16* __restrict__ G,
    const _Float16* __restrict__ w1eT, const _Float16* __restrict__ w2eT,
    float* __restrict__ out) {
  __shared__ float xv[64][96];
  __shared__ alignas(16) _Float16 As[5][64 * 32];
  __shared__ uint8_t pa[544], pb[544];
  const int t = threadIdx.x;
  const size_t n0 = (size_t)blockIdx.x * 64;
  const int phase = blockIdx.y;
  for (int idx = t; idx < 64 * 96; idx += 256)
    xv[idx / 96][idx % 96] = xv_g[(n0 + idx / 96) * 96 + idx % 96];
  for (int p = t; p < 544; p += 256) {
    int a = 0, b = 0;
    if (phase == 0) {
      if (p < A1C) { triu_ab(p, 31, a, b); b += 1; }
    } else {
      if (p < P1C) triu_ab(p, 32, a, b);
    }
    pa[p] = (uint8_t)a; pb[p] = (uint8_t)b;
  }
  const int lane = t & 63, wave = t >> 6;
  const int m16 = lane & 15, quad = lane >> 4;
  const int sw8 = (quad ^ ((m16 >> 1) & 3)) * 8;
  const int br = t >> 2;
  const int bc8 = ((t & 3) ^ ((br >> 1) & 3)) * 8;  // swizzled source chunk
  const int lc8 = (t & 3) * 8;                      // LDS column
  const float s2 = 0.70710678118654752f, s6 = 0.40824829046386302f;
  __syncthreads();

  if (phase == 0) {  // ---- o1e: cross pairs ----
    floatx4 acc[3] = {};
    for (int k0 = 0; k0 < 512; k0 += 32) {
      if (k0) __syncthreads();
      {
        half8 g8 = *(const half8*)&G[(n0 + br) * NP2 + (M0C + M1C) + k0 + bc8];
        half8 a0, a1, a2;
#pragma unroll
        for (int j = 0; j < 8; ++j) {
          int p = k0 + bc8 + j;
          if (p < A1C) {
            int a = pa[p], b = pb[p];
            float ax = xv[br][a * 3], ay = xv[br][a * 3 + 1], az = xv[br][a * 3 + 2];
            float bx = xv[br][b * 3], by = xv[br][b * 3 + 1], bz = xv[br][b * 3 + 2];
            float g = (float)g8[j] * s2;
            a0[j] = (_Float16)((ay * bz - az * by) * g);
            a1[j] = (_Float16)((az * bx - ax * bz) * g);
            a2[j] = (_Float16)((ax * by - ay * bx) * g);
          } else {
            a0[j] = (_Float16)0.f; a1[j] = (_Float16)0.f; a2[j] = (_Float16)0.f;
          }
        }
        *(half8*)&As[0][br * 32 + lc8] = a0;
        *(half8*)&As[1][br * 32 + lc8] = a1;
        *(half8*)&As[2][br * 32 + lc8] = a2;
      }
      __syncthreads();
      half8 bf = *(const half8*)&w1eT[(size_t)m16 * 512 + k0 + quad * 8];
#pragma unroll
      for (int i = 0; i < 3; ++i) {
        half8 af = *(const half8*)&As[i][(wave * 16 + m16) * 32 + sw8];
        acc[i] = __builtin_amdgcn_mfma_f32_16x16x32_f16(af, bf, acc[i], 0, 0, 0);
      }
    }
#pragma unroll
    for (int i = 0; i < 3; ++i)
#pragma unroll
      for (int rr = 0; rr < 4; ++rr)
        out[(n0 + wave * 16 + quad * 4 + rr) * 288 + 160 + m16 * 3 + i] = acc[i][rr];
  } else {  // ---- o2: symmetric pairs ----
    floatx4 acc[5] = {};
    for (int k0 = 0; k0 < 544; k0 += 32) {
      if (k0) __syncthreads();
      {
        half8 g8 = *(const half8*)&G[(n0 + br) * NP2 + (M0C + M1C + A1C) + k0 + bc8];
        half8 m0v, m1v, m2v, m3v, m4v;
#pragma unroll
        for (int j = 0; j < 8; ++j) {
          int p = k0 + bc8 + j;
          if (p < P1C) {
            int a = pa[p], b = pb[p];
            float ax = xv[br][a * 3], ay = xv[br][a * 3 + 1], az = xv[br][a * 3 + 2];
            float bx = xv[br][b * 3], by = xv[br][b * 3 + 1], bz = xv[br][b * 3 + 2];
            float c1 = (a == b) ? s2 : 1.f;
            float gw = (float)g8[j] * c1;
            m0v[j] = (_Float16)(s2 * (ax * by + ay * bx) * gw);
            m1v[j] = (_Float16)(s2 * (ay * bz + az * by) * gw);
            m2v[j] = (_Float16)(s2 * (ax * bz + az * bx) * gw);
            m3v[j] = (_Float16)(s2 * (ax * bx - ay * by) * gw);
            m4v[j] = (_Float16)(s6 * (2.f * az * bz - ax * bx - ay * by) * gw);
          } else {
            m0v[j] = (_Float16)0.f; m1v[j] = (_Float16)0.f; m2v[j] = (_Float16)0.f;
            m3v[j] = (_Float16)0.f; m4v[j] = (_Float16)0.f;
          }
        }
        *(half8*)&As[0][br * 32 + lc8] = m0v;
        *(half8*)&As[1][br * 32 + lc8] = m1v;
        *(half8*)&As[2][br * 32 + lc8] = m2v;
        *(half8*)&As[3][br * 32 + lc8] = m3v;
        *(half8*)&As[4][br * 32 + lc8] = m4v;
      }
      __syncthreads();
      half8 bf = *(const half8*)&w2eT[(size_t)m16 * 544 + k0 + quad * 8];
#pragma unroll
      for (int m = 0; m < 5; ++m) {
        half8 af = *(const half8*)&As[m][(wave * 16 + m16) * 32 + sw8];
        acc[m] = __builtin_amdgcn_mfma_f32_16x16x32_f16(af, bf, acc[m], 0, 0, 0);
      }
    }
#pragma unroll
    for (int m = 0; m < 5; ++m)
#pragma unroll
      for (int rr = 0; rr < 4; ++rr)
        out[(n0 + wave * 16 + quad * 4 + rr) * 288 + 208 + m16 * 5 + m] = acc[m][rr];
  }
}

// ---------------------------------------------------------------------------
extern "C" void kernel_launch(void* const* d_in, const int* in_sizes, int n_in,
                              void* d_out, int out_size, void* d_ws, size_t ws_size,
                              hipStream_t stream) {
  const float* xs  = (const float*)d_in[0];
  const float* xv  = (const float*)d_in[1];
  const float* w1  = (const float*)d_in[2];
  const float* w2  = (const float*)d_in[3];
  const float* w0  = (const float*)d_in[4];
  const float* w1o = (const float*)d_in[5];
  const float* w1e = (const float*)d_in[6];
  const float* w2e = (const float*)d_in[7];
  float* out = (float*)d_out;

  char* ws = (char*)d_ws;
  size_t off = 0;
  _Float16* w1T = (_Float16*)(ws + off); off += (size_t)NPAD1 * KP * 2;    // 15.14 MB
  _Float16* w2T = (_Float16*)(ws + off); off += (size_t)NP2 * KP * 2;      // 31.65 MB
  _Float16* f0p = (_Float16*)(ws + off); off += (size_t)N_ROWS * KP * 2;   // 44.04 MB
  _Float16* H   = (_Float16*)(ws + off); off += (size_t)N_ROWS * NPAD1 * 2;// 46.14 MB
  _Float16* G   = (_Float16*)(ws + off);                                   // 96.47 MB
  // total ~233.4 MB

  // Small epilogue weights live inside w1T's region (dead after GEMM1).
  _Float16* w0T  = w1T;                                     // 64 x 2688 = 344064 B
  _Float16* w1oT = (_Float16*)((char*)w1T + 344064);        // 32 x 2112 = 135168 B
  _Float16* w1eT = (_Float16*)((char*)w1T + 479232);        // 32 x 512  =  32768 B
  _Float16* w2eT = (_Float16*)((char*)w1T + 512000);        // 32 x 544  =  34816 B

  transpose_cvt_kernel<<<dim3(KP / 32, NPAD1 / 32), 256, 0, stream>>>(w1, w1T, M0C, M0C, KP);
  transpose_cvt_kernel<<<dim3(KP / 32, NP2 / 32), 256, 0, stream>>>(w2, w2T, M0C, NIR, KP);
  build_f0_kernel<<<N_ROWS, 256, 0, stream>>>(xs, xv, f0p);
  gemm256_kernel<true><<<dim3(NPAD1 / 256, N_ROWS / 256), 512, 0, stream>>>(
      f0p, w1T, H, KP, KP, KP, NPAD1);
  // w1T now dead -> overwrite with epilogue weights
  transpose_cvt_kernel<<<dim3(KP / 32, 2), 256, 0, stream>>>(w0, w0T, M0C, 64, KP);
  transpose_cvt_kernel<<<dim3(M1P / 32, 1), 256, 0, stream>>>(w1o, w1oT, M1C, 32, M1P);
  transpose_cvt_kernel<<<dim3(16, 1), 256, 0, stream>>>(w1e, w1eT, A1C, 16, 512);
  transpose_cvt_kernel<<<dim3(17, 1), 256, 0, stream>>>(w2e, w2eT, P1C, 16, 544);
  gemm256_kernel<false><<<dim3(NP2 / 256, N_ROWS / 256), 512, 0, stream>>>(
      H, w2T, G, KP, NPAD1, KP, NP2);
  epi0_kernel<<<256, 256, 0, stream>>>(f0p, G, w0T, out);
  epi1_kernel<<<256, 256, 0, stream>>>(xs, xv, G, w1oT, out);
  epi1e2_kernel<<<dim3(128, 2), 256, 0, stream>>>(xv, G, w1eT, w2eT, out);
}